// Round 9
// baseline (321.181 us; speedup 1.0000x reference)
//
#include <hip/hip_runtime.h>
#include <math.h>

// Shapes (fixed): L=512 B=4 D=1024 H=16 DH=64 FF=4096 HP=32 K=256, LK=768

typedef __bf16 bf16x8 __attribute__((ext_vector_type(8)));
typedef float f32x4 __attribute__((ext_vector_type(4)));

__device__ __forceinline__ unsigned short f2bf(float f) {
  unsigned u = __float_as_uint(f);
  u = (u + 0x7fffu + ((u >> 16) & 1u)) >> 16;
  return (unsigned short)u;
}
__device__ __forceinline__ float bf2f(unsigned short s) {
  return __uint_as_float(((unsigned)s) << 16);
}

__device__ __forceinline__ void gload_lds16(const void* g, void* l) {
  __builtin_amdgcn_global_load_lds(
      (__attribute__((address_space(1))) void*)g,
      (__attribute__((address_space(3))) void*)l, 16, 0, 0);
}

// ---- prep_all: weight transposes + top-LN + gathered-row LN + pos table -----
// blocks [0,6144): transposes; [6144,9216): LN rows; [9216,9228): posk
__global__ __launch_bounds__(256) void prep_all(
    const float* __restrict__ wq, const float* __restrict__ wk, const float* __restrict__ wv,
    const float* __restrict__ wo, const float* __restrict__ fc1, const float* __restrict__ fc2,
    const float* __restrict__ x, const int* __restrict__ oc, const int* __restrict__ pos_ids,
    const float* __restrict__ tln_g, const float* __restrict__ tln_b,
    unsigned short* __restrict__ qkvT, unsigned short* __restrict__ woT,
    unsigned short* __restrict__ fc1T, unsigned short* __restrict__ fc2T,
    unsigned short* __restrict__ kvb, int* __restrict__ posk) {
  __shared__ float smem[64 * 33];
  const int id = blockIdx.x, t = threadIdx.x;

  if (id < 6144) {  // ---- weight transpose branch (64k x 32n tiles) ----
    const float* W; unsigned short* WT; int Kd, Nd, n0, k0;
    if (id < 2048) {
      int which = id >> 9, lid = id & 511;
      W = which == 0 ? wq : (which == 1 ? wk : (which == 2 ? wv : wo));
      WT = which < 3 ? qkvT + (long)which * 1024 * 1024 : woT;
      Kd = 1024; Nd = 1024;
      k0 = (lid >> 5) * 64; n0 = (lid & 31) * 32;
    } else if (id < 4096) {
      int lid = id - 2048;
      W = fc1; WT = fc1T; Kd = 1024; Nd = 4096;
      k0 = (lid >> 7) * 64; n0 = (lid & 127) * 32;
    } else {
      int lid = id - 4096;
      W = fc2; WT = fc2T; Kd = 4096; Nd = 1024;
      k0 = (lid >> 5) * 64; n0 = (lid & 31) * 32;
    }
    const int tx = t & 31, ty = t >> 5;  // 32 x 8
#pragma unroll
    for (int j = 0; j < 64; j += 8)
      smem[(ty + j) * 33 + tx] = W[(long)(k0 + ty + j) * Nd + n0 + tx];
    __syncthreads();
#pragma unroll
    for (int i = 0; i < 32; i += 8) {
      ushort2 o;
      o.x = f2bf(smem[(2 * tx) * 33 + ty + i]);
      o.y = f2bf(smem[(2 * tx + 1) * 33 + ty + i]);
      *(ushort2*)&WT[(long)(n0 + ty + i) * Kd + k0 + 2 * tx] = o;
    }
  } else if (id < 9216) {  // ---- LN branch: kvb row = LN(x[src row]) ----
    const int rowIdx = id - 6144;  // 0..3071
    int srow;
    if (rowIdx < 2048) {
      srow = rowIdx;
    } else {
      int j = (rowIdx - 2048) >> 2, b = rowIdx & 3;
      srow = oc[b * 256 + j] * 4 + b;
    }
    const float4 vv = *(const float4*)(x + (long)srow * 1024 + t * 4);
    float s = vv.x + vv.y + vv.z + vv.w;
    float ss = vv.x * vv.x + vv.y * vv.y + vv.z * vv.z + vv.w * vv.w;
#pragma unroll
    for (int o = 32; o > 0; o >>= 1) { s += __shfl_down(s, o); ss += __shfl_down(ss, o); }
    const int wave = t >> 6, lane = t & 63;
    if (lane == 0) { smem[wave] = s; smem[4 + wave] = ss; }
    __syncthreads();
    s = smem[0] + smem[1] + smem[2] + smem[3];
    ss = smem[4] + smem[5] + smem[6] + smem[7];
    const float mean = s * (1.f / 1024.f);
    const float rstd = rsqrtf(ss * (1.f / 1024.f) - mean * mean + 1e-5f);
    const float4 gg = *(const float4*)(tln_g + t * 4);
    const float4 bbv = *(const float4*)(tln_b + t * 4);
    ushort4 o;
    o.x = f2bf((vv.x - mean) * rstd * gg.x + bbv.x);
    o.y = f2bf((vv.y - mean) * rstd * gg.y + bbv.y);
    o.z = f2bf((vv.z - mean) * rstd * gg.z + bbv.z);
    o.w = f2bf((vv.w - mean) * rstd * gg.w + bbv.w);
    *(ushort4*)&kvb[(long)rowIdx * 1024 + t * 4] = o;
  } else {  // ---- posk branch ----
    int i = (id - 9216) * 256 + t;
    if (i < 3072) {
      int s = i >> 2, b = i & 3;
      posk[i] = (s < 512) ? pos_ids[b * 512 + s]
                          : pos_ids[b * 512 + oc[b * 256 + s - 512]];
    }
  }
}

// ------- fused: v = p0 + p1 + R; Xout = v; Y = bf16(LN(v)) -------------------
__global__ __launch_bounds__(256) void red_ln(
    const float* __restrict__ p0, const float* __restrict__ p1,
    const float* __restrict__ R, float* __restrict__ Xout,
    const float* __restrict__ g, const float* __restrict__ bb,
    unsigned short* __restrict__ Y) {
  const int row = blockIdx.x, t = threadIdx.x;
  const long base4 = (long)row * 256 + t;
  const float4 a = ((const float4*)p0)[base4];
  const float4 b4 = ((const float4*)p1)[base4];
  const float4 r4 = ((const float4*)R)[base4];
  float4 v;
  v.x = a.x + b4.x + r4.x; v.y = a.y + b4.y + r4.y;
  v.z = a.z + b4.z + r4.z; v.w = a.w + b4.w + r4.w;
  ((float4*)Xout)[base4] = v;
  float s = v.x + v.y + v.z + v.w;
  float ss = v.x * v.x + v.y * v.y + v.z * v.z + v.w * v.w;
#pragma unroll
  for (int o = 32; o > 0; o >>= 1) { s += __shfl_down(s, o); ss += __shfl_down(ss, o); }
  __shared__ float red[8];
  const int wave = t >> 6, lane = t & 63;
  if (lane == 0) { red[wave] = s; red[4 + wave] = ss; }
  __syncthreads();
  s = red[0] + red[1] + red[2] + red[3];
  ss = red[4] + red[5] + red[6] + red[7];
  const float mean = s * (1.f / 1024.f);
  const float rstd = rsqrtf(ss * (1.f / 1024.f) - mean * mean + 1e-5f);
  const float4 gg = *(const float4*)(g + t * 4);
  const float4 bbv = *(const float4*)(bb + t * 4);
  ushort4 o;
  o.x = f2bf((v.x - mean) * rstd * gg.x + bbv.x);
  o.y = f2bf((v.y - mean) * rstd * gg.y + bbv.y);
  o.z = f2bf((v.z - mean) * rstd * gg.z + bbv.z);
  o.w = f2bf((v.w - mean) * rstd * gg.w + bbv.w);
  ((ushort4*)Y)[base4] = o;
}

// ------- fused: reduce+residual+LN (f32) + pair head (silu @ w2) -------------
__global__ __launch_bounds__(256) void red_ln_pair(
    const float* __restrict__ p0, const float* __restrict__ p1,
    const float* __restrict__ R, float* __restrict__ Xout,
    const float* __restrict__ g, const float* __restrict__ bb,
    const float* __restrict__ w1, const float* __restrict__ w2,
    float* __restrict__ xpi) {
  const int row = blockIdx.x, t = threadIdx.x;
  const long base4 = (long)row * 256 + t;
  __shared__ float lnrow[1024];
  __shared__ float red[8];
  __shared__ float red2[64][4];
  __shared__ float s1[64];
  const float4 a = ((const float4*)p0)[base4];
  const float4 b4 = ((const float4*)p1)[base4];
  const float4 r4 = ((const float4*)R)[base4];
  float4 v;
  v.x = a.x + b4.x + r4.x; v.y = a.y + b4.y + r4.y;
  v.z = a.z + b4.z + r4.z; v.w = a.w + b4.w + r4.w;
  ((float4*)Xout)[base4] = v;
  float s = v.x + v.y + v.z + v.w;
  float ss = v.x * v.x + v.y * v.y + v.z * v.z + v.w * v.w;
#pragma unroll
  for (int o = 32; o > 0; o >>= 1) { s += __shfl_down(s, o); ss += __shfl_down(ss, o); }
  const int wave = t >> 6, lane = t & 63;
  if (lane == 0) { red[wave] = s; red[4 + wave] = ss; }
  __syncthreads();
  s = red[0] + red[1] + red[2] + red[3];
  ss = red[4] + red[5] + red[6] + red[7];
  const float mean = s * (1.f / 1024.f);
  const float rstd = rsqrtf(ss * (1.f / 1024.f) - mean * mean + 1e-5f);
  const float4 gg = *(const float4*)(g + t * 4);
  const float4 bbv = *(const float4*)(bb + t * 4);
  float4 ln;
  ln.x = (v.x - mean) * rstd * gg.x + bbv.x;
  ln.y = (v.y - mean) * rstd * gg.y + bbv.y;
  ln.z = (v.z - mean) * rstd * gg.z + bbv.z;
  ln.w = (v.w - mean) * rstd * gg.w + bbv.w;
  *(float4*)&lnrow[t * 4] = ln;
  __syncthreads();
  const int c = t & 63, qt = t >> 6;
  float acc = 0.f;
  for (int k = qt * 256; k < qt * 256 + 256; k++)
    acc += lnrow[k] * w1[k * 64 + c];
  red2[c][qt] = acc;
  __syncthreads();
  if (t < 64) {
    float vv = red2[t][0] + red2[t][1] + red2[t][2] + red2[t][3];
    s1[t] = vv / (1.f + __expf(-vv));  // silu
  }
  __syncthreads();
  if (t < 32) {
    float o = 0.f;
    for (int k = 0; k < 64; k++) o += s1[k] * w2[k * 32 + t];
    xpi[(long)row * 32 + t] = o;
  }
}

// ---------------- MFMA bf16 NT GEMM, 128x128 tile, BK=32 ---------------------
// EPI: 0 = f32 out, 1 = f32 out + R, 2 = bf16 gelu(out), 3 = bf16 out
template <int EPI>
__global__ __launch_bounds__(256) void gemm_nt(
    const unsigned short* __restrict__ A, const unsigned short* __restrict__ BT,
    void* __restrict__ Cout, const float* __restrict__ R, int M, int N, int Kd) {
  __shared__ __align__(16) unsigned short As[128 * 32];
  __shared__ __align__(16) unsigned short Bs[128 * 32];
  const int t = threadIdx.x;
  const int wave = t >> 6, lane = t & 63;
  const int m0 = blockIdx.y * 128, n0 = blockIdx.x * 128;
  const int wr = wave >> 1, wc = wave & 1;
  const int lr = lane & 15, lg = lane >> 4;

  f32x4 acc[4][4] = {};

  const int srow = 32 * wave + (lane >> 2);
  const int schunk = (lane & 3) * 8;
  const unsigned short* Ag = A + (long)(m0 + srow) * Kd + schunk;
  const unsigned short* Bg = BT + (long)(n0 + srow) * Kd + schunk;
  unsigned short* AsW = &As[(32 * wave) * 32];
  unsigned short* BsW = &Bs[(32 * wave) * 32];

  for (int k0 = 0; k0 < Kd; k0 += 32) {
    __syncthreads();
    gload_lds16(Ag + k0, AsW);
    gload_lds16(Ag + k0 + 16 * (long)Kd, AsW + 16 * 32);
    gload_lds16(Bg + k0, BsW);
    gload_lds16(Bg + k0 + 16 * (long)Kd, BsW + 16 * 32);
    asm volatile("s_waitcnt vmcnt(0)" ::: "memory");
    __syncthreads();

    bf16x8 af[4], bfr[4];
#pragma unroll
    for (int mf = 0; mf < 4; mf++)
      af[mf] = *(const bf16x8*)&As[(64 * wr + 16 * mf + lr) * 32 + lg * 8];
#pragma unroll
    for (int nf = 0; nf < 4; nf++)
      bfr[nf] = *(const bf16x8*)&Bs[(64 * wc + 16 * nf + lr) * 32 + lg * 8];
#pragma unroll
    for (int mf = 0; mf < 4; mf++)
#pragma unroll
      for (int nf = 0; nf < 4; nf++)
        acc[mf][nf] = __builtin_amdgcn_mfma_f32_16x16x32_bf16(af[mf], bfr[nf], acc[mf][nf], 0, 0, 0);
  }

#pragma unroll
  for (int mf = 0; mf < 4; mf++)
#pragma unroll
    for (int nf = 0; nf < 4; nf++)
#pragma unroll
      for (int r = 0; r < 4; r++) {
        const int row = m0 + 64 * wr + 16 * mf + 4 * lg + r;
        const int col = n0 + 64 * wc + 16 * nf + lr;
        const long off = (long)row * N + col;
        float v = acc[mf][nf][r];
        if constexpr (EPI == 1) {
          ((float*)Cout)[off] = v + R[off];
        } else if constexpr (EPI == 2) {
          float gl = 0.5f * v * (1.0f + erff(v * 0.70710678118654752f));
          ((unsigned short*)Cout)[off] = f2bf(gl);
        } else if constexpr (EPI == 3) {
          ((unsigned short*)Cout)[off] = f2bf(v);
        } else {
          ((float*)Cout)[off] = v;
        }
      }
}

// -------- QKV GEMM: 1D grid, dead Q tiles (m>=16, n<8) skipped ---------------
__global__ __launch_bounds__(256) void gemm_qkv(
    const unsigned short* __restrict__ A, const unsigned short* __restrict__ BT,
    unsigned short* __restrict__ Cout) {
  constexpr int N = 3072, Kd = 1024;
  int bid = blockIdx.x;
  int mt, nt;
  if (bid < 384) { mt = bid / 24; nt = bid % 24; }
  else { int rem = bid - 384; mt = 16 + (rem >> 4); nt = 8 + (rem & 15); }
  const int m0 = mt * 128, n0 = nt * 128;

  __shared__ __align__(16) unsigned short As[128 * 32];
  __shared__ __align__(16) unsigned short Bs[128 * 32];
  const int t = threadIdx.x;
  const int wave = t >> 6, lane = t & 63;
  const int wr = wave >> 1, wc = wave & 1;
  const int lr = lane & 15, lg = lane >> 4;

  f32x4 acc[4][4] = {};

  const int srow = 32 * wave + (lane >> 2);
  const int schunk = (lane & 3) * 8;
  const unsigned short* Ag = A + (long)(m0 + srow) * Kd + schunk;
  const unsigned short* Bg = BT + (long)(n0 + srow) * Kd + schunk;
  unsigned short* AsW = &As[(32 * wave) * 32];
  unsigned short* BsW = &Bs[(32 * wave) * 32];

  for (int k0 = 0; k0 < Kd; k0 += 32) {
    __syncthreads();
    gload_lds16(Ag + k0, AsW);
    gload_lds16(Ag + k0 + 16 * (long)Kd, AsW + 16 * 32);
    gload_lds16(Bg + k0, BsW);
    gload_lds16(Bg + k0 + 16 * (long)Kd, BsW + 16 * 32);
    asm volatile("s_waitcnt vmcnt(0)" ::: "memory");
    __syncthreads();

    bf16x8 af[4], bfr[4];
#pragma unroll
    for (int mf = 0; mf < 4; mf++)
      af[mf] = *(const bf16x8*)&As[(64 * wr + 16 * mf + lr) * 32 + lg * 8];
#pragma unroll
    for (int nf = 0; nf < 4; nf++)
      bfr[nf] = *(const bf16x8*)&Bs[(64 * wc + 16 * nf + lr) * 32 + lg * 8];
#pragma unroll
    for (int mf = 0; mf < 4; mf++)
#pragma unroll
      for (int nf = 0; nf < 4; nf++)
        acc[mf][nf] = __builtin_amdgcn_mfma_f32_16x16x32_bf16(af[mf], bfr[nf], acc[mf][nf], 0, 0, 0);
  }

#pragma unroll
  for (int mf = 0; mf < 4; mf++)
#pragma unroll
    for (int nf = 0; nf < 4; nf++)
#pragma unroll
      for (int r = 0; r < 4; r++) {
        const int row = m0 + 64 * wr + 16 * mf + 4 * lg + r;
        const int col = n0 + 64 * wc + 16 * nf + lr;
        Cout[(long)row * N + col] = f2bf(acc[mf][nf][r]);
      }
}

// ------------ split-K=2 variant: partial f32 C per blockIdx.z ----------------
__global__ __launch_bounds__(256) void gemm_nt_splitk(
    const unsigned short* __restrict__ A, const unsigned short* __restrict__ BT,
    float* __restrict__ Cp, int M, int N, int Kd) {
  const int kh = Kd >> 1;
  const long kbase = (long)blockIdx.z * kh;
  const unsigned short* A2 = A + kbase;
  const unsigned short* B2 = BT + kbase;
  float* Cz = Cp + (long)blockIdx.z * M * N;

  __shared__ __align__(16) unsigned short As[128 * 32];
  __shared__ __align__(16) unsigned short Bs[128 * 32];
  const int t = threadIdx.x;
  const int wave = t >> 6, lane = t & 63;
  const int m0 = blockIdx.y * 128, n0 = blockIdx.x * 128;
  const int wr = wave >> 1, wc = wave & 1;
  const int lr = lane & 15, lg = lane >> 4;

  f32x4 acc[4][4] = {};

  const int srow = 32 * wave + (lane >> 2);
  const int schunk = (lane & 3) * 8;
  const unsigned short* Ag = A2 + (long)(m0 + srow) * Kd + schunk;
  const unsigned short* Bg = B2 + (long)(n0 + srow) * Kd + schunk;
  unsigned short* AsW = &As[(32 * wave) * 32];
  unsigned short* BsW = &Bs[(32 * wave) * 32];

  for (int k0 = 0; k0 < kh; k0 += 32) {
    __syncthreads();
    gload_lds16(Ag + k0, AsW);
    gload_lds16(Ag + k0 + 16 * (long)Kd, AsW + 16 * 32);
    gload_lds16(Bg + k0, BsW);
    gload_lds16(Bg + k0 + 16 * (long)Kd, BsW + 16 * 32);
    asm volatile("s_waitcnt vmcnt(0)" ::: "memory");
    __syncthreads();

    bf16x8 af[4], bfr[4];
#pragma unroll
    for (int mf = 0; mf < 4; mf++)
      af[mf] = *(const bf16x8*)&As[(64 * wr + 16 * mf + lr) * 32 + lg * 8];
#pragma unroll
    for (int nf = 0; nf < 4; nf++)
      bfr[nf] = *(const bf16x8*)&Bs[(64 * wc + 16 * nf + lr) * 32 + lg * 8];
#pragma unroll
    for (int mf = 0; mf < 4; mf++)
#pragma unroll
      for (int nf = 0; nf < 4; nf++)
        acc[mf][nf] = __builtin_amdgcn_mfma_f32_16x16x32_bf16(af[mf], bfr[nf], acc[mf][nf], 0, 0, 0);
  }

#pragma unroll
  for (int mf = 0; mf < 4; mf++)
#pragma unroll
    for (int nf = 0; nf < 4; nf++)
#pragma unroll
      for (int r = 0; r < 4; r++) {
        const int row = m0 + 64 * wr + 16 * mf + 4 * lg + r;
        const int col = n0 + 64 * wc + 16 * nf + lr;
        Cz[(long)row * N + col] = acc[mf][nf][r];
      }
}

// ---- rope_vt: RoPE split (blocks < 5120, ushort2) + V transpose (>= 5120) ---
// qb: [bh][512][64] bf16 scaled 1/8;  kbh: [bh][768][64];  vth: [bh][64][768]
__global__ __launch_bounds__(256) void rope_vt(
    const unsigned short* __restrict__ QKV, const int* __restrict__ posk,
    unsigned short* __restrict__ qb, unsigned short* __restrict__ kbh,
    unsigned short* __restrict__ vth) {
  const int bid = blockIdx.x, t = threadIdx.x;
  if (bid < 5120) {  // ---- RoPE branch: 2 dp per thread ----
    int idx = bid * 256 + t;  // 524288 q-pairs + 786432 k-pairs
    bool isq = idx < 524288;
    int rp = isq ? idx : idx - 524288;
    int p = rp & 255;          // 256 threads per row
    int row = rp >> 8;         // row = s*4+b
    int hh = p >> 4, dpp = (p & 15) * 2;
    int s = row >> 2, b = row & 3;
    int pos = posk[s * 4 + b];
    const unsigned short* src = QKV + (long)row * 3072 + (isq ? 0 : 1024) + hh * 64 + dpp;
    ushort2 xa = *(const ushort2*)src;         // dp, dp+1 (first half)
    ushort2 xb = *(const ushort2*)(src + 32);  // dp+32, dp+33 (second half)
    const float cfr = 0.41524101186091903f;    // log2(10000)/32
    float i0 = exp2f(-(float)dpp * cfr);
    float i1 = exp2f(-(float)(dpp + 1) * cfr);
    float s0, c0, s1, c1;
    __sincosf((float)pos * i0, &s0, &c0);
    __sincosf((float)pos * i1, &s1, &c1);
    float x1a = bf2f(xa.x), x1b = bf2f(xa.y);
    float x2a = bf2f(xb.x), x2b = bf2f(xb.y);
    float qs = isq ? 0.125f : 1.0f;
    ushort2 o1, o2;
    o1.x = f2bf((x1a * c0 - x2a * s0) * qs);
    o1.y = f2bf((x1b * c1 - x2b * s1) * qs);
    o2.x = f2bf((x1a * s0 + x2a * c0) * qs);
    o2.y = f2bf((x1b * s1 + x2b * c1) * qs);
    unsigned short* dst = (isq ? qb + ((long)(b * 16 + hh) * 512 + s) * 64
                               : kbh + ((long)(b * 16 + hh) * 768 + s) * 64) + dpp;
    *(ushort2*)dst = o1;
    *(ushort2*)(dst + 32) = o2;
  } else {  // ---- V transpose branch ----
    __shared__ unsigned short tile[64][72];
    const int vb = bid - 5120;           // 0..767
    const int kt = vb % 12, bh = vb / 12;
    const int b = bh >> 4, h = bh & 15;
    const int key = t >> 2, c = t & 3;
    const unsigned short* src =
        QKV + ((long)(kt * 64 + key) * 4 + b) * 3072 + 2048 + h * 64 + c * 16;
#pragma unroll
    for (int j = 0; j < 16; j++) tile[c * 16 + j][key] = src[j];
    __syncthreads();
    const int d = t >> 2;
    unsigned short* dst = vth + ((long)bh * 64 + d) * 768 + kt * 64 + c * 16;
    *(uint4*)dst = *(const uint4*)&tile[d][c * 16];
    *(uint4*)(dst + 8) = *(const uint4*)&tile[d][c * 16 + 8];
  }
}

// -- MFMA flash attention, barrier-free: fragments direct from global (L1/L2) -
__global__ __launch_bounds__(512) void att_mfma(
    const unsigned short* __restrict__ qb, const unsigned short* __restrict__ kbh,
    const unsigned short* __restrict__ vth,
    const unsigned char* __restrict__ pad_mask, const unsigned char* __restrict__ exp_mask,
    unsigned short* __restrict__ o_bf) {
  const int bh = blockIdx.y, b = bh >> 4, h = bh & 15;
  const int q0 = blockIdx.x * 128;
  const int t = threadIdx.x, wave = t >> 6, lane = t & 63;
  const int lr = lane & 15, lg = lane >> 4;

  __shared__ __align__(16) unsigned short Ps[8][16][72];
  __shared__ float maskAdd[768];

  for (int i = t; i < 768; i += 512)
    maskAdd[i] = ((i < 512) ? pad_mask[b * 512 + i] : exp_mask[b * 256 + i - 512]) ? -1e9f : 0.f;

  const unsigned short* qrow = qb + ((long)bh * 512 + q0 + wave * 16 + lr) * 64;
  const bf16x8 aq0 = *(const bf16x8*)(qrow + lg * 8);
  const bf16x8 aq1 = *(const bf16x8*)(qrow + 32 + lg * 8);
  __syncthreads();  // maskAdd ready; no further barriers in the K-loop

  float m_run[4] = {-1e30f, -1e30f, -1e30f, -1e30f};
  float l_run[4] = {0.f, 0.f, 0.f, 0.f};
  f32x4 Oacc[4] = {};

  const unsigned short* kb0 = kbh + (long)bh * 768 * 64;
  const unsigned short* vb0 = vth + (long)bh * 64 * 768;

  for (int kt = 0; kt < 12; ++kt) {
    float sv[4][4];
#pragma unroll
    for (int nf = 0; nf < 4; nf++) {
      const unsigned short* kr = kb0 + (long)(kt * 64 + nf * 16 + lr) * 64;
      f32x4 z = {};
      bf16x8 b0 = *(const bf16x8*)(kr + lg * 8);
      bf16x8 b1 = *(const bf16x8*)(kr + 32 + lg * 8);
      z = __builtin_amdgcn_mfma_f32_16x16x32_bf16(aq0, b0, z, 0, 0, 0);
      z = __builtin_amdgcn_mfma_f32_16x16x32_bf16(aq1, b1, z, 0, 0, 0);
      float ma = maskAdd[kt * 64 + nf * 16 + lr];
#pragma unroll
      for (int r = 0; r < 4; r++) sv[nf][r] = z[r] + ma;
    }
    float mnew[4], scale[4], rs[4];
#pragma unroll
    for (int r = 0; r < 4; r++) {
      float tm = fmaxf(fmaxf(sv[0][r], sv[1][r]), fmaxf(sv[2][r], sv[3][r]));
      tm = fmaxf(tm, __shfl_xor(tm, 1));
      tm = fmaxf(tm, __shfl_xor(tm, 2));
      tm = fmaxf(tm, __shfl_xor(tm, 4));
      tm = fmaxf(tm, __shfl_xor(tm, 8));
      mnew[r] = fmaxf(m_run[r], tm);
      scale[r] = __expf(m_run[r] - mnew[r]);
      m_run[r] = mnew[r];
      rs[r] = 0.f;
    }
#pragma unroll
    for (int nf = 0; nf < 4; nf++)
#pragma unroll
      for (int r = 0; r < 4; r++) {
        float p = __expf(sv[nf][r] - mnew[r]);
        rs[r] += p;
        Ps[wave][lg * 4 + r][nf * 16 + lr] = f2bf(p);
      }
#pragma unroll
    for (int r = 0; r < 4; r++) {
      float x = rs[r];
      x += __shfl_xor(x, 1); x += __shfl_xor(x, 2);
      x += __shfl_xor(x, 4); x += __shfl_xor(x, 8);
      l_run[r] = l_run[r] * scale[r] + x;
#pragma unroll
      for (int nf = 0; nf < 4; nf++) Oacc[nf][r] *= scale[r];
    }
    bf16x8 ap0 = *(const bf16x8*)&Ps[wave][lr][lg * 8];
    bf16x8 ap1 = *(const bf16x8*)&Ps[wave][lr][32 + lg * 8];
#pragma unroll
    for (int nf = 0; nf < 4; nf++) {
      const unsigned short* vr = vb0 + (long)(nf * 16 + lr) * 768 + kt * 64;
      bf16x8 b0 = *(const bf16x8*)(vr + lg * 8);
      bf16x8 b1 = *(const bf16x8*)(vr + 32 + lg * 8);
      Oacc[nf] = __builtin_amdgcn_mfma_f32_16x16x32_bf16(ap0, b0, Oacc[nf], 0, 0, 0);
      Oacc[nf] = __builtin_amdgcn_mfma_f32_16x16x32_bf16(ap1, b1, Oacc[nf], 0, 0, 0);
    }
  }

#pragma unroll
  for (int r = 0; r < 4; r++) {
    float inv = 1.0f / l_run[r];
    int l = q0 + wave * 16 + lg * 4 + r;
#pragma unroll
    for (int nf = 0; nf < 4; nf++)
      o_bf[(((long)l * 4 + b) * 16 + h) * 64 + nf * 16 + lr] = f2bf(Oacc[nf][r] * inv);
  }
}

// ---- x_pair += outer(x_p_i, x_p_j), grid-stride (2048 blocks) ----------------
__global__ __launch_bounds__(256) void pair_update(
    const float* __restrict__ x_pair, const float* __restrict__ xpi,
    const int* __restrict__ oc, float* __restrict__ out) {
  for (int idx4 = blockIdx.x * 256 + threadIdx.x; idx4 < 12582912; idx4 += 2048 * 256) {
    int h4 = idx4 & 7;
    int lkb = idx4 >> 3;
    int b = lkb & 3;
    int lk = lkb >> 2;
    int kk = lk % 768;
    int l = lk / 768;
    int src = (kk < 512) ? kk : oc[b * 256 + kk - 512];
    float4 pv = ((const float4*)x_pair)[idx4];
    float4 a = ((const float4*)xpi)[(l * 4 + b) * 8 + h4];
    float4 bb = ((const float4*)xpi)[(src * 4 + b) * 8 + h4];
    float4 o;
    o.x = pv.x + a.x * bb.x; o.y = pv.y + a.y * bb.y;
    o.z = pv.z + a.z * bb.z; o.w = pv.w + a.w * bb.w;
    ((float4*)out)[idx4] = o;
  }
}

// =============================== launcher ====================================
extern "C" void kernel_launch(void* const* d_in, const int* in_sizes, int n_in,
                              void* d_out, int out_size, void* d_ws, size_t ws_size,
                              hipStream_t stream) {
  const float* x        = (const float*)d_in[0];
  const float* x_pair   = (const float*)d_in[1];
  const unsigned char* pad_mask = (const unsigned char*)d_in[2];
  const unsigned char* exp_mask = (const unsigned char*)d_in[3];
  const int* pos_ids    = (const int*)d_in[4];
  const int* oc         = (const int*)d_in[5];
  const float* wq  = (const float*)d_in[6];
  const float* wk  = (const float*)d_in[7];
  const float* wv  = (const float*)d_in[8];
  const float* wo  = (const float*)d_in[9];
  const float* fc1 = (const float*)d_in[10];
  const float* fc2 = (const float*)d_in[11];
  const float* tln_g = (const float*)d_in[12];
  const float* tln_b = (const float*)d_in[13];
  const float* mln_g = (const float*)d_in[14];
  const float* mln_b = (const float*)d_in[15];
  const float* pln_g = (const float*)d_in[16];
  const float* pln_b = (const float*)d_in[17];
  const float* w1 = (const float*)d_in[18];
  const float* w2 = (const float*)d_in[19];

  char* wsp = (char*)d_ws;
  size_t off = 0;
  auto alloc = [&](size_t bytes) -> void* {
    void* p = wsp + off;
    off = (off + bytes + 255) & ~(size_t)255;
    return p;
  };
  unsigned short* qkvT = (unsigned short*)alloc(3072LL * 1024 * 2);
  unsigned short* woT  = (unsigned short*)alloc(1024LL * 1024 * 2);
  unsigned short* fc1T = (unsigned short*)alloc(4096LL * 1024 * 2);
  unsigned short* fc2T = (unsigned short*)alloc(1024LL * 4096 * 2);
  unsigned short* kvb  = (unsigned short*)alloc(3072LL * 1024 * 2);
  int* posk            = (int*)alloc(3072LL * 4);
  unsigned short* QKVb = (unsigned short*)alloc(3072LL * 3072 * 2);
  unsigned short* qb   = (unsigned short*)alloc(64LL * 512 * 64 * 2);
  unsigned short* kbh  = (unsigned short*)alloc(64LL * 768 * 64 * 2);
  unsigned short* vth  = (unsigned short*)alloc(64LL * 64 * 768 * 2);
  unsigned short* obf  = (unsigned short*)alloc(2048LL * 1024 * 2);
  float* x1            = (float*)alloc(2048LL * 1024 * 4);
  unsigned short* h2   = (unsigned short*)alloc(2048LL * 1024 * 2);
  unsigned short* gbf  = (unsigned short*)alloc(2048LL * 4096 * 2);
  float* xpi           = (float*)alloc(2048LL * 32 * 4);
  float* pp            = (float*)alloc(2LL * 2048 * 1024 * 4);  // split-K partials
  (void)ws_size; (void)in_sizes; (void)n_in; (void)out_size;

  // prep: weight transposes + top-LN (incl. gathered rows) + pos table
  prep_all<<<9228, 256, 0, stream>>>(wq, wk, wv, wo, fc1, fc2, x, oc, pos_ids,
                                     tln_g, tln_b, qkvT, woT, fc1T, fc2T, kvb, posk);

  // QKV GEMM (dead Q tiles skipped), bf16 out
  gemm_qkv<<<512, 256, 0, stream>>>(kvb, qkvT, QKVb);

  // RoPE split + V transpose in one launch
  rope_vt<<<5888, 256, 0, stream>>>(QKVb, posk, qb, kbh, vth);

  att_mfma<<<dim3(4, 64), 512, 0, stream>>>(qb, kbh, vth, pad_mask, exp_mask, obf);

  // x1 = x + attn_out @ wo  (split-K=2 + fused reduce+residual+LN -> h2)
  gemm_nt_splitk<<<dim3(8, 16, 2), 256, 0, stream>>>(obf, woT, pp, 2048, 1024, 1024);
  red_ln<<<2048, 256, 0, stream>>>(pp, pp + 2097152, x, x1, mln_g, mln_b, h2);

  gemm_nt<2><<<dim3(32, 16), 256, 0, stream>>>(h2, fc1T, gbf, nullptr, 2048, 4096, 1024);

  // x = x1 + gelu @ fc2  (split-K=2 + fused reduce+residual+LN+pairhead)
  gemm_nt_splitk<<<dim3(8, 16, 2), 256, 0, stream>>>(gbf, fc2T, pp, 2048, 1024, 4096);
  red_ln_pair<<<2048, 256, 0, stream>>>(pp, pp + 2097152, x1, (float*)d_out,
                                        pln_g, pln_b, w1, w2, xpi);

  pair_update<<<2048, 256, 0, stream>>>(x_pair, xpi, oc, (float*)d_out + 2097152);
}

// Round 10
// 309.320 us; speedup vs baseline: 1.0383x; 1.0383x over previous
//
#include <hip/hip_runtime.h>
#include <math.h>

// Shapes (fixed): L=512 B=4 D=1024 H=16 DH=64 FF=4096 HP=32 K=256, LK=768

typedef __bf16 bf16x8 __attribute__((ext_vector_type(8)));
typedef float f32x4 __attribute__((ext_vector_type(4)));

__device__ __forceinline__ unsigned short f2bf(float f) {
  unsigned u = __float_as_uint(f);
  u = (u + 0x7fffu + ((u >> 16) & 1u)) >> 16;
  return (unsigned short)u;
}
__device__ __forceinline__ float bf2f(unsigned short s) {
  return __uint_as_float(((unsigned)s) << 16);
}

__device__ __forceinline__ void gload_lds16(const void* g, void* l) {
  __builtin_amdgcn_global_load_lds(
      (__attribute__((address_space(1))) void*)g,
      (__attribute__((address_space(3))) void*)l, 16, 0, 0);
}

// ---- prep_all: weight transposes + top-LN + gathered-row LN + pos table -----
// blocks [0,6144): transposes; [6144,9216): LN rows; [9216,9228): posk
__global__ __launch_bounds__(256) void prep_all(
    const float* __restrict__ wq, const float* __restrict__ wk, const float* __restrict__ wv,
    const float* __restrict__ wo, const float* __restrict__ fc1, const float* __restrict__ fc2,
    const float* __restrict__ x, const int* __restrict__ oc, const int* __restrict__ pos_ids,
    const float* __restrict__ tln_g, const float* __restrict__ tln_b,
    unsigned short* __restrict__ qkvT, unsigned short* __restrict__ woT,
    unsigned short* __restrict__ fc1T, unsigned short* __restrict__ fc2T,
    unsigned short* __restrict__ kvb, int* __restrict__ posk) {
  __shared__ float smem[64 * 33];
  const int id = blockIdx.x, t = threadIdx.x;

  if (id < 6144) {  // ---- weight transpose branch (64k x 32n tiles) ----
    const float* W; unsigned short* WT; int Kd, Nd, n0, k0;
    if (id < 2048) {
      int which = id >> 9, lid = id & 511;
      W = which == 0 ? wq : (which == 1 ? wk : (which == 2 ? wv : wo));
      WT = which < 3 ? qkvT + (long)which * 1024 * 1024 : woT;
      Kd = 1024; Nd = 1024;
      k0 = (lid >> 5) * 64; n0 = (lid & 31) * 32;
    } else if (id < 4096) {
      int lid = id - 2048;
      W = fc1; WT = fc1T; Kd = 1024; Nd = 4096;
      k0 = (lid >> 7) * 64; n0 = (lid & 127) * 32;
    } else {
      int lid = id - 4096;
      W = fc2; WT = fc2T; Kd = 4096; Nd = 1024;
      k0 = (lid >> 5) * 64; n0 = (lid & 31) * 32;
    }
    const int tx = t & 31, ty = t >> 5;  // 32 x 8
#pragma unroll
    for (int j = 0; j < 64; j += 8)
      smem[(ty + j) * 33 + tx] = W[(long)(k0 + ty + j) * Nd + n0 + tx];
    __syncthreads();
#pragma unroll
    for (int i = 0; i < 32; i += 8) {
      ushort2 o;
      o.x = f2bf(smem[(2 * tx) * 33 + ty + i]);
      o.y = f2bf(smem[(2 * tx + 1) * 33 + ty + i]);
      *(ushort2*)&WT[(long)(n0 + ty + i) * Kd + k0 + 2 * tx] = o;
    }
  } else if (id < 9216) {  // ---- LN branch: kvb row = LN(x[src row]) ----
    const int rowIdx = id - 6144;  // 0..3071
    int srow;
    if (rowIdx < 2048) {
      srow = rowIdx;
    } else {
      int j = (rowIdx - 2048) >> 2, b = rowIdx & 3;
      srow = oc[b * 256 + j] * 4 + b;
    }
    const float4 vv = *(const float4*)(x + (long)srow * 1024 + t * 4);
    float s = vv.x + vv.y + vv.z + vv.w;
    float ss = vv.x * vv.x + vv.y * vv.y + vv.z * vv.z + vv.w * vv.w;
#pragma unroll
    for (int o = 32; o > 0; o >>= 1) { s += __shfl_down(s, o); ss += __shfl_down(ss, o); }
    const int wave = t >> 6, lane = t & 63;
    if (lane == 0) { smem[wave] = s; smem[4 + wave] = ss; }
    __syncthreads();
    s = smem[0] + smem[1] + smem[2] + smem[3];
    ss = smem[4] + smem[5] + smem[6] + smem[7];
    const float mean = s * (1.f / 1024.f);
    const float rstd = rsqrtf(ss * (1.f / 1024.f) - mean * mean + 1e-5f);
    const float4 gg = *(const float4*)(tln_g + t * 4);
    const float4 bbv = *(const float4*)(tln_b + t * 4);
    ushort4 o;
    o.x = f2bf((vv.x - mean) * rstd * gg.x + bbv.x);
    o.y = f2bf((vv.y - mean) * rstd * gg.y + bbv.y);
    o.z = f2bf((vv.z - mean) * rstd * gg.z + bbv.z);
    o.w = f2bf((vv.w - mean) * rstd * gg.w + bbv.w);
    *(ushort4*)&kvb[(long)rowIdx * 1024 + t * 4] = o;
  } else {  // ---- posk branch ----
    int i = (id - 9216) * 256 + t;
    if (i < 3072) {
      int s = i >> 2, b = i & 3;
      posk[i] = (s < 512) ? pos_ids[b * 512 + s]
                          : pos_ids[b * 512 + oc[b * 256 + s - 512]];
    }
  }
}

// ------- fused: v = p0 + p1 + R; Xout = v; Y = bf16(LN(v)) -------------------
__global__ __launch_bounds__(256) void red_ln(
    const float* __restrict__ p0, const float* __restrict__ p1,
    const float* __restrict__ R, float* __restrict__ Xout,
    const float* __restrict__ g, const float* __restrict__ bb,
    unsigned short* __restrict__ Y) {
  const int row = blockIdx.x, t = threadIdx.x;
  const long base4 = (long)row * 256 + t;
  const float4 a = ((const float4*)p0)[base4];
  const float4 b4 = ((const float4*)p1)[base4];
  const float4 r4 = ((const float4*)R)[base4];
  float4 v;
  v.x = a.x + b4.x + r4.x; v.y = a.y + b4.y + r4.y;
  v.z = a.z + b4.z + r4.z; v.w = a.w + b4.w + r4.w;
  ((float4*)Xout)[base4] = v;
  float s = v.x + v.y + v.z + v.w;
  float ss = v.x * v.x + v.y * v.y + v.z * v.z + v.w * v.w;
#pragma unroll
  for (int o = 32; o > 0; o >>= 1) { s += __shfl_down(s, o); ss += __shfl_down(ss, o); }
  __shared__ float red[8];
  const int wave = t >> 6, lane = t & 63;
  if (lane == 0) { red[wave] = s; red[4 + wave] = ss; }
  __syncthreads();
  s = red[0] + red[1] + red[2] + red[3];
  ss = red[4] + red[5] + red[6] + red[7];
  const float mean = s * (1.f / 1024.f);
  const float rstd = rsqrtf(ss * (1.f / 1024.f) - mean * mean + 1e-5f);
  const float4 gg = *(const float4*)(g + t * 4);
  const float4 bbv = *(const float4*)(bb + t * 4);
  ushort4 o;
  o.x = f2bf((v.x - mean) * rstd * gg.x + bbv.x);
  o.y = f2bf((v.y - mean) * rstd * gg.y + bbv.y);
  o.z = f2bf((v.z - mean) * rstd * gg.z + bbv.z);
  o.w = f2bf((v.w - mean) * rstd * gg.w + bbv.w);
  ((ushort4*)Y)[base4] = o;
}

// ------- fused: reduce+residual+LN (f32) + pair head (silu @ w2) -------------
__global__ __launch_bounds__(256) void red_ln_pair(
    const float* __restrict__ p0, const float* __restrict__ p1,
    const float* __restrict__ R, float* __restrict__ Xout,
    const float* __restrict__ g, const float* __restrict__ bb,
    const float* __restrict__ w1, const float* __restrict__ w2,
    float* __restrict__ xpi) {
  const int row = blockIdx.x, t = threadIdx.x;
  const long base4 = (long)row * 256 + t;
  __shared__ float lnrow[1024];
  __shared__ float red[8];
  __shared__ float red2[64][4];
  __shared__ float s1[64];
  const float4 a = ((const float4*)p0)[base4];
  const float4 b4 = ((const float4*)p1)[base4];
  const float4 r4 = ((const float4*)R)[base4];
  float4 v;
  v.x = a.x + b4.x + r4.x; v.y = a.y + b4.y + r4.y;
  v.z = a.z + b4.z + r4.z; v.w = a.w + b4.w + r4.w;
  ((float4*)Xout)[base4] = v;
  float s = v.x + v.y + v.z + v.w;
  float ss = v.x * v.x + v.y * v.y + v.z * v.z + v.w * v.w;
#pragma unroll
  for (int o = 32; o > 0; o >>= 1) { s += __shfl_down(s, o); ss += __shfl_down(ss, o); }
  const int wave = t >> 6, lane = t & 63;
  if (lane == 0) { red[wave] = s; red[4 + wave] = ss; }
  __syncthreads();
  s = red[0] + red[1] + red[2] + red[3];
  ss = red[4] + red[5] + red[6] + red[7];
  const float mean = s * (1.f / 1024.f);
  const float rstd = rsqrtf(ss * (1.f / 1024.f) - mean * mean + 1e-5f);
  const float4 gg = *(const float4*)(g + t * 4);
  const float4 bbv = *(const float4*)(bb + t * 4);
  float4 ln;
  ln.x = (v.x - mean) * rstd * gg.x + bbv.x;
  ln.y = (v.y - mean) * rstd * gg.y + bbv.y;
  ln.z = (v.z - mean) * rstd * gg.z + bbv.z;
  ln.w = (v.w - mean) * rstd * gg.w + bbv.w;
  *(float4*)&lnrow[t * 4] = ln;
  __syncthreads();
  const int c = t & 63, qt = t >> 6;
  float acc = 0.f;
  for (int k = qt * 256; k < qt * 256 + 256; k++)
    acc += lnrow[k] * w1[k * 64 + c];
  red2[c][qt] = acc;
  __syncthreads();
  if (t < 64) {
    float vv = red2[t][0] + red2[t][1] + red2[t][2] + red2[t][3];
    s1[t] = vv / (1.f + __expf(-vv));  // silu
  }
  __syncthreads();
  if (t < 32) {
    float o = 0.f;
    for (int k = 0; k < 64; k++) o += s1[k] * w2[k * 32 + t];
    xpi[(long)row * 32 + t] = o;
  }
}

// ---------------- MFMA bf16 NT GEMM, 128x128 tile, BK=32 ---------------------
// EPI: 0 = f32 out, 1 = f32 out + R, 2 = bf16 gelu(out), 3 = bf16 out
template <int EPI>
__global__ __launch_bounds__(256) void gemm_nt(
    const unsigned short* __restrict__ A, const unsigned short* __restrict__ BT,
    void* __restrict__ Cout, const float* __restrict__ R, int M, int N, int Kd) {
  __shared__ __align__(16) unsigned short As[128 * 32];
  __shared__ __align__(16) unsigned short Bs[128 * 32];
  const int t = threadIdx.x;
  const int wave = t >> 6, lane = t & 63;
  const int m0 = blockIdx.y * 128, n0 = blockIdx.x * 128;
  const int wr = wave >> 1, wc = wave & 1;
  const int lr = lane & 15, lg = lane >> 4;

  f32x4 acc[4][4] = {};

  const int srow = 32 * wave + (lane >> 2);
  const int schunk = (lane & 3) * 8;
  const unsigned short* Ag = A + (long)(m0 + srow) * Kd + schunk;
  const unsigned short* Bg = BT + (long)(n0 + srow) * Kd + schunk;
  unsigned short* AsW = &As[(32 * wave) * 32];
  unsigned short* BsW = &Bs[(32 * wave) * 32];

  for (int k0 = 0; k0 < Kd; k0 += 32) {
    __syncthreads();
    gload_lds16(Ag + k0, AsW);
    gload_lds16(Ag + k0 + 16 * (long)Kd, AsW + 16 * 32);
    gload_lds16(Bg + k0, BsW);
    gload_lds16(Bg + k0 + 16 * (long)Kd, BsW + 16 * 32);
    asm volatile("s_waitcnt vmcnt(0)" ::: "memory");
    __syncthreads();

    bf16x8 af[4], bfr[4];
#pragma unroll
    for (int mf = 0; mf < 4; mf++)
      af[mf] = *(const bf16x8*)&As[(64 * wr + 16 * mf + lr) * 32 + lg * 8];
#pragma unroll
    for (int nf = 0; nf < 4; nf++)
      bfr[nf] = *(const bf16x8*)&Bs[(64 * wc + 16 * nf + lr) * 32 + lg * 8];
#pragma unroll
    for (int mf = 0; mf < 4; mf++)
#pragma unroll
      for (int nf = 0; nf < 4; nf++)
        acc[mf][nf] = __builtin_amdgcn_mfma_f32_16x16x32_bf16(af[mf], bfr[nf], acc[mf][nf], 0, 0, 0);
  }

#pragma unroll
  for (int mf = 0; mf < 4; mf++)
#pragma unroll
    for (int nf = 0; nf < 4; nf++)
#pragma unroll
      for (int r = 0; r < 4; r++) {
        const int row = m0 + 64 * wr + 16 * mf + 4 * lg + r;
        const int col = n0 + 64 * wc + 16 * nf + lr;
        const long off = (long)row * N + col;
        float v = acc[mf][nf][r];
        if constexpr (EPI == 1) {
          ((float*)Cout)[off] = v + R[off];
        } else if constexpr (EPI == 2) {
          float gl = 0.5f * v * (1.0f + erff(v * 0.70710678118654752f));
          ((unsigned short*)Cout)[off] = f2bf(gl);
        } else if constexpr (EPI == 3) {
          ((unsigned short*)Cout)[off] = f2bf(v);
        } else {
          ((float*)Cout)[off] = v;
        }
      }
}

// -------- QKV GEMM: 1D grid, dead Q tiles (m>=16, n<8) skipped ---------------
__global__ __launch_bounds__(256) void gemm_qkv(
    const unsigned short* __restrict__ A, const unsigned short* __restrict__ BT,
    unsigned short* __restrict__ Cout) {
  constexpr int N = 3072, Kd = 1024;
  int bid = blockIdx.x;
  int mt, nt;
  if (bid < 384) { mt = bid / 24; nt = bid % 24; }
  else { int rem = bid - 384; mt = 16 + (rem >> 4); nt = 8 + (rem & 15); }
  const int m0 = mt * 128, n0 = nt * 128;

  __shared__ __align__(16) unsigned short As[128 * 32];
  __shared__ __align__(16) unsigned short Bs[128 * 32];
  const int t = threadIdx.x;
  const int wave = t >> 6, lane = t & 63;
  const int wr = wave >> 1, wc = wave & 1;
  const int lr = lane & 15, lg = lane >> 4;

  f32x4 acc[4][4] = {};

  const int srow = 32 * wave + (lane >> 2);
  const int schunk = (lane & 3) * 8;
  const unsigned short* Ag = A + (long)(m0 + srow) * Kd + schunk;
  const unsigned short* Bg = BT + (long)(n0 + srow) * Kd + schunk;
  unsigned short* AsW = &As[(32 * wave) * 32];
  unsigned short* BsW = &Bs[(32 * wave) * 32];

  for (int k0 = 0; k0 < Kd; k0 += 32) {
    __syncthreads();
    gload_lds16(Ag + k0, AsW);
    gload_lds16(Ag + k0 + 16 * (long)Kd, AsW + 16 * 32);
    gload_lds16(Bg + k0, BsW);
    gload_lds16(Bg + k0 + 16 * (long)Kd, BsW + 16 * 32);
    asm volatile("s_waitcnt vmcnt(0)" ::: "memory");
    __syncthreads();

    bf16x8 af[4], bfr[4];
#pragma unroll
    for (int mf = 0; mf < 4; mf++)
      af[mf] = *(const bf16x8*)&As[(64 * wr + 16 * mf + lr) * 32 + lg * 8];
#pragma unroll
    for (int nf = 0; nf < 4; nf++)
      bfr[nf] = *(const bf16x8*)&Bs[(64 * wc + 16 * nf + lr) * 32 + lg * 8];
#pragma unroll
    for (int mf = 0; mf < 4; mf++)
#pragma unroll
      for (int nf = 0; nf < 4; nf++)
        acc[mf][nf] = __builtin_amdgcn_mfma_f32_16x16x32_bf16(af[mf], bfr[nf], acc[mf][nf], 0, 0, 0);
  }

#pragma unroll
  for (int mf = 0; mf < 4; mf++)
#pragma unroll
    for (int nf = 0; nf < 4; nf++)
#pragma unroll
      for (int r = 0; r < 4; r++) {
        const int row = m0 + 64 * wr + 16 * mf + 4 * lg + r;
        const int col = n0 + 64 * wc + 16 * nf + lr;
        Cout[(long)row * N + col] = f2bf(acc[mf][nf][r]);
      }
}

// ------------ split-K=2 variant: partial f32 C per blockIdx.z ----------------
__global__ __launch_bounds__(256) void gemm_nt_splitk(
    const unsigned short* __restrict__ A, const unsigned short* __restrict__ BT,
    float* __restrict__ Cp, int M, int N, int Kd) {
  const int kh = Kd >> 1;
  const long kbase = (long)blockIdx.z * kh;
  const unsigned short* A2 = A + kbase;
  const unsigned short* B2 = BT + kbase;
  float* Cz = Cp + (long)blockIdx.z * M * N;

  __shared__ __align__(16) unsigned short As[128 * 32];
  __shared__ __align__(16) unsigned short Bs[128 * 32];
  const int t = threadIdx.x;
  const int wave = t >> 6, lane = t & 63;
  const int m0 = blockIdx.y * 128, n0 = blockIdx.x * 128;
  const int wr = wave >> 1, wc = wave & 1;
  const int lr = lane & 15, lg = lane >> 4;

  f32x4 acc[4][4] = {};

  const int srow = 32 * wave + (lane >> 2);
  const int schunk = (lane & 3) * 8;
  const unsigned short* Ag = A2 + (long)(m0 + srow) * Kd + schunk;
  const unsigned short* Bg = B2 + (long)(n0 + srow) * Kd + schunk;
  unsigned short* AsW = &As[(32 * wave) * 32];
  unsigned short* BsW = &Bs[(32 * wave) * 32];

  for (int k0 = 0; k0 < kh; k0 += 32) {
    __syncthreads();
    gload_lds16(Ag + k0, AsW);
    gload_lds16(Ag + k0 + 16 * (long)Kd, AsW + 16 * 32);
    gload_lds16(Bg + k0, BsW);
    gload_lds16(Bg + k0 + 16 * (long)Kd, BsW + 16 * 32);
    asm volatile("s_waitcnt vmcnt(0)" ::: "memory");
    __syncthreads();

    bf16x8 af[4], bfr[4];
#pragma unroll
    for (int mf = 0; mf < 4; mf++)
      af[mf] = *(const bf16x8*)&As[(64 * wr + 16 * mf + lr) * 32 + lg * 8];
#pragma unroll
    for (int nf = 0; nf < 4; nf++)
      bfr[nf] = *(const bf16x8*)&Bs[(64 * wc + 16 * nf + lr) * 32 + lg * 8];
#pragma unroll
    for (int mf = 0; mf < 4; mf++)
#pragma unroll
      for (int nf = 0; nf < 4; nf++)
        acc[mf][nf] = __builtin_amdgcn_mfma_f32_16x16x32_bf16(af[mf], bfr[nf], acc[mf][nf], 0, 0, 0);
  }

#pragma unroll
  for (int mf = 0; mf < 4; mf++)
#pragma unroll
    for (int nf = 0; nf < 4; nf++)
#pragma unroll
      for (int r = 0; r < 4; r++) {
        const int row = m0 + 64 * wr + 16 * mf + 4 * lg + r;
        const int col = n0 + 64 * wc + 16 * nf + lr;
        Cz[(long)row * N + col] = acc[mf][nf][r];
      }
}

// ---- rope_vt: RoPE split (blocks < 5120, ushort2) + V transpose (>= 5120) ---
// qb: [bh][512][64] bf16 scaled 1/8;  kbh: [bh][768][64];  vth: [bh][64][768]
__global__ __launch_bounds__(256) void rope_vt(
    const unsigned short* __restrict__ QKV, const int* __restrict__ posk,
    unsigned short* __restrict__ qb, unsigned short* __restrict__ kbh,
    unsigned short* __restrict__ vth) {
  const int bid = blockIdx.x, t = threadIdx.x;
  if (bid < 5120) {  // ---- RoPE branch: 2 dp per thread ----
    int idx = bid * 256 + t;  // 524288 q-pairs + 786432 k-pairs
    bool isq = idx < 524288;
    int rp = isq ? idx : idx - 524288;
    int p = rp & 255;          // 256 threads per row
    int row = rp >> 8;         // row = s*4+b
    int hh = p >> 4, dpp = (p & 15) * 2;
    int s = row >> 2, b = row & 3;
    int pos = posk[s * 4 + b];
    const unsigned short* src = QKV + (long)row * 3072 + (isq ? 0 : 1024) + hh * 64 + dpp;
    ushort2 xa = *(const ushort2*)src;         // dp, dp+1 (first half)
    ushort2 xb = *(const ushort2*)(src + 32);  // dp+32, dp+33 (second half)
    const float cfr = 0.41524101186091903f;    // log2(10000)/32
    float i0 = exp2f(-(float)dpp * cfr);
    float i1 = exp2f(-(float)(dpp + 1) * cfr);
    float s0, c0, s1, c1;
    __sincosf((float)pos * i0, &s0, &c0);
    __sincosf((float)pos * i1, &s1, &c1);
    float x1a = bf2f(xa.x), x1b = bf2f(xa.y);
    float x2a = bf2f(xb.x), x2b = bf2f(xb.y);
    float qs = isq ? 0.125f : 1.0f;
    ushort2 o1, o2;
    o1.x = f2bf((x1a * c0 - x2a * s0) * qs);
    o1.y = f2bf((x1b * c1 - x2b * s1) * qs);
    o2.x = f2bf((x1a * s0 + x2a * c0) * qs);
    o2.y = f2bf((x1b * s1 + x2b * c1) * qs);
    unsigned short* dst = (isq ? qb + ((long)(b * 16 + hh) * 512 + s) * 64
                               : kbh + ((long)(b * 16 + hh) * 768 + s) * 64) + dpp;
    *(ushort2*)dst = o1;
    *(ushort2*)(dst + 32) = o2;
  } else {  // ---- V transpose branch ----
    __shared__ unsigned short tile[64][72];
    const int vb = bid - 5120;           // 0..767
    const int kt = vb % 12, bh = vb / 12;
    const int b = bh >> 4, h = bh & 15;
    const int key = t >> 2, c = t & 3;
    const unsigned short* src =
        QKV + ((long)(kt * 64 + key) * 4 + b) * 3072 + 2048 + h * 64 + c * 16;
#pragma unroll
    for (int j = 0; j < 16; j++) tile[c * 16 + j][key] = src[j];
    __syncthreads();
    const int d = t >> 2;
    unsigned short* dst = vth + ((long)bh * 64 + d) * 768 + kt * 64 + c * 16;
    *(uint4*)dst = *(const uint4*)&tile[d][c * 16];
    *(uint4*)(dst + 8) = *(const uint4*)&tile[d][c * 16 + 8];
  }
}

// -- MFMA flash attention, barrier-free: fragments direct from global (L1/L2) -
__global__ __launch_bounds__(512) void att_mfma(
    const unsigned short* __restrict__ qb, const unsigned short* __restrict__ kbh,
    const unsigned short* __restrict__ vth,
    const unsigned char* __restrict__ pad_mask, const unsigned char* __restrict__ exp_mask,
    unsigned short* __restrict__ o_bf) {
  const int bh = blockIdx.y, b = bh >> 4, h = bh & 15;
  const int q0 = blockIdx.x * 128;
  const int t = threadIdx.x, wave = t >> 6, lane = t & 63;
  const int lr = lane & 15, lg = lane >> 4;

  __shared__ __align__(16) unsigned short Ps[8][16][72];
  __shared__ float maskAdd[768];

  for (int i = t; i < 768; i += 512)
    maskAdd[i] = ((i < 512) ? pad_mask[b * 512 + i] : exp_mask[b * 256 + i - 512]) ? -1e9f : 0.f;

  const unsigned short* qrow = qb + ((long)bh * 512 + q0 + wave * 16 + lr) * 64;
  const bf16x8 aq0 = *(const bf16x8*)(qrow + lg * 8);
  const bf16x8 aq1 = *(const bf16x8*)(qrow + 32 + lg * 8);
  __syncthreads();  // maskAdd ready; no further barriers in the K-loop

  float m_run[4] = {-1e30f, -1e30f, -1e30f, -1e30f};
  float l_run[4] = {0.f, 0.f, 0.f, 0.f};
  f32x4 Oacc[4] = {};

  const unsigned short* kb0 = kbh + (long)bh * 768 * 64;
  const unsigned short* vb0 = vth + (long)bh * 64 * 768;

  for (int kt = 0; kt < 12; ++kt) {
    float sv[4][4];
#pragma unroll
    for (int nf = 0; nf < 4; nf++) {
      const unsigned short* kr = kb0 + (long)(kt * 64 + nf * 16 + lr) * 64;
      f32x4 z = {};
      bf16x8 b0 = *(const bf16x8*)(kr + lg * 8);
      bf16x8 b1 = *(const bf16x8*)(kr + 32 + lg * 8);
      z = __builtin_amdgcn_mfma_f32_16x16x32_bf16(aq0, b0, z, 0, 0, 0);
      z = __builtin_amdgcn_mfma_f32_16x16x32_bf16(aq1, b1, z, 0, 0, 0);
      float ma = maskAdd[kt * 64 + nf * 16 + lr];
#pragma unroll
      for (int r = 0; r < 4; r++) sv[nf][r] = z[r] + ma;
    }
    float mnew[4], scale[4], rs[4];
#pragma unroll
    for (int r = 0; r < 4; r++) {
      float tm = fmaxf(fmaxf(sv[0][r], sv[1][r]), fmaxf(sv[2][r], sv[3][r]));
      tm = fmaxf(tm, __shfl_xor(tm, 1));
      tm = fmaxf(tm, __shfl_xor(tm, 2));
      tm = fmaxf(tm, __shfl_xor(tm, 4));
      tm = fmaxf(tm, __shfl_xor(tm, 8));
      mnew[r] = fmaxf(m_run[r], tm);
      scale[r] = __expf(m_run[r] - mnew[r]);
      m_run[r] = mnew[r];
      rs[r] = 0.f;
    }
#pragma unroll
    for (int nf = 0; nf < 4; nf++)
#pragma unroll
      for (int r = 0; r < 4; r++) {
        float p = __expf(sv[nf][r] - mnew[r]);
        rs[r] += p;
        Ps[wave][lg * 4 + r][nf * 16 + lr] = f2bf(p);
      }
#pragma unroll
    for (int r = 0; r < 4; r++) {
      float x = rs[r];
      x += __shfl_xor(x, 1); x += __shfl_xor(x, 2);
      x += __shfl_xor(x, 4); x += __shfl_xor(x, 8);
      l_run[r] = l_run[r] * scale[r] + x;
#pragma unroll
      for (int nf = 0; nf < 4; nf++) Oacc[nf][r] *= scale[r];
    }
    bf16x8 ap0 = *(const bf16x8*)&Ps[wave][lr][lg * 8];
    bf16x8 ap1 = *(const bf16x8*)&Ps[wave][lr][32 + lg * 8];
#pragma unroll
    for (int nf = 0; nf < 4; nf++) {
      const unsigned short* vr = vb0 + (long)(nf * 16 + lr) * 768 + kt * 64;
      bf16x8 b0 = *(const bf16x8*)(vr + lg * 8);
      bf16x8 b1 = *(const bf16x8*)(vr + 32 + lg * 8);
      Oacc[nf] = __builtin_amdgcn_mfma_f32_16x16x32_bf16(ap0, b0, Oacc[nf], 0, 0, 0);
      Oacc[nf] = __builtin_amdgcn_mfma_f32_16x16x32_bf16(ap1, b1, Oacc[nf], 0, 0, 0);
    }
  }

#pragma unroll
  for (int r = 0; r < 4; r++) {
    float inv = 1.0f / l_run[r];
    int l = q0 + wave * 16 + lg * 4 + r;
#pragma unroll
    for (int nf = 0; nf < 4; nf++)
      o_bf[(((long)l * 4 + b) * 16 + h) * 64 + nf * 16 + lr] = f2bf(Oacc[nf][r] * inv);
  }
}

// ------------ x_pair += outer(x_p_i, x_p_j) with inline oc gather ------------
// Flat grid (49152 blocks): one float4 per thread, max memory-level parallelism.
__global__ __launch_bounds__(256) void pair_update(
    const float* __restrict__ x_pair, const float* __restrict__ xpi,
    const int* __restrict__ oc, float* __restrict__ out) {
  int idx4 = blockIdx.x * 256 + threadIdx.x;  // 12582912 float4s
  int h4 = idx4 & 7;
  int lkb = idx4 >> 3;
  int b = lkb & 3;
  int lk = lkb >> 2;
  int kk = lk % 768;
  int l = lk / 768;
  int src = (kk < 512) ? kk : oc[b * 256 + kk - 512];
  float4 pv = ((const float4*)x_pair)[idx4];
  float4 a = ((const float4*)xpi)[(l * 4 + b) * 8 + h4];
  float4 bb = ((const float4*)xpi)[(src * 4 + b) * 8 + h4];
  float4 o;
  o.x = pv.x + a.x * bb.x; o.y = pv.y + a.y * bb.y;
  o.z = pv.z + a.z * bb.z; o.w = pv.w + a.w * bb.w;
  ((float4*)out)[idx4] = o;
}

// =============================== launcher ====================================
extern "C" void kernel_launch(void* const* d_in, const int* in_sizes, int n_in,
                              void* d_out, int out_size, void* d_ws, size_t ws_size,
                              hipStream_t stream) {
  const float* x        = (const float*)d_in[0];
  const float* x_pair   = (const float*)d_in[1];
  const unsigned char* pad_mask = (const unsigned char*)d_in[2];
  const unsigned char* exp_mask = (const unsigned char*)d_in[3];
  const int* pos_ids    = (const int*)d_in[4];
  const int* oc         = (const int*)d_in[5];
  const float* wq  = (const float*)d_in[6];
  const float* wk  = (const float*)d_in[7];
  const float* wv  = (const float*)d_in[8];
  const float* wo  = (const float*)d_in[9];
  const float* fc1 = (const float*)d_in[10];
  const float* fc2 = (const float*)d_in[11];
  const float* tln_g = (const float*)d_in[12];
  const float* tln_b = (const float*)d_in[13];
  const float* mln_g = (const float*)d_in[14];
  const float* mln_b = (const float*)d_in[15];
  const float* pln_g = (const float*)d_in[16];
  const float* pln_b = (const float*)d_in[17];
  const float* w1 = (const float*)d_in[18];
  const float* w2 = (const float*)d_in[19];

  char* wsp = (char*)d_ws;
  size_t off = 0;
  auto alloc = [&](size_t bytes) -> void* {
    void* p = wsp + off;
    off = (off + bytes + 255) & ~(size_t)255;
    return p;
  };
  unsigned short* qkvT = (unsigned short*)alloc(3072LL * 1024 * 2);
  unsigned short* woT  = (unsigned short*)alloc(1024LL * 1024 * 2);
  unsigned short* fc1T = (unsigned short*)alloc(4096LL * 1024 * 2);
  unsigned short* fc2T = (unsigned short*)alloc(1024LL * 4096 * 2);
  unsigned short* kvb  = (unsigned short*)alloc(3072LL * 1024 * 2);
  int* posk            = (int*)alloc(3072LL * 4);
  unsigned short* QKVb = (unsigned short*)alloc(3072LL * 3072 * 2);
  unsigned short* qb   = (unsigned short*)alloc(64LL * 512 * 64 * 2);
  unsigned short* kbh  = (unsigned short*)alloc(64LL * 768 * 64 * 2);
  unsigned short* vth  = (unsigned short*)alloc(64LL * 64 * 768 * 2);
  unsigned short* obf  = (unsigned short*)alloc(2048LL * 1024 * 2);
  float* x1            = (float*)alloc(2048LL * 1024 * 4);
  unsigned short* h2   = (unsigned short*)alloc(2048LL * 1024 * 2);
  unsigned short* gbf  = (unsigned short*)alloc(2048LL * 4096 * 2);
  float* xpi           = (float*)alloc(2048LL * 32 * 4);
  float* pp            = (float*)alloc(2LL * 2048 * 1024 * 4);  // split-K partials
  (void)ws_size; (void)in_sizes; (void)n_in; (void)out_size;

  // prep: weight transposes + top-LN (incl. gathered rows) + pos table
  prep_all<<<9228, 256, 0, stream>>>(wq, wk, wv, wo, fc1, fc2, x, oc, pos_ids,
                                     tln_g, tln_b, qkvT, woT, fc1T, fc2T, kvb, posk);

  // QKV GEMM (dead Q tiles skipped), bf16 out
  gemm_qkv<<<512, 256, 0, stream>>>(kvb, qkvT, QKVb);

  // RoPE split + V transpose in one launch
  rope_vt<<<5888, 256, 0, stream>>>(QKVb, posk, qb, kbh, vth);

  att_mfma<<<dim3(4, 64), 512, 0, stream>>>(qb, kbh, vth, pad_mask, exp_mask, obf);

  // x1 = x + attn_out @ wo  (split-K=2 + fused reduce+residual+LN -> h2)
  gemm_nt_splitk<<<dim3(8, 16, 2), 256, 0, stream>>>(obf, woT, pp, 2048, 1024, 1024);
  red_ln<<<2048, 256, 0, stream>>>(pp, pp + 2097152, x, x1, mln_g, mln_b, h2);

  gemm_nt<2><<<dim3(32, 16), 256, 0, stream>>>(h2, fc1T, gbf, nullptr, 2048, 4096, 1024);

  // x = x1 + gelu @ fc2  (split-K=2 + fused reduce+residual+LN+pairhead)
  gemm_nt_splitk<<<dim3(8, 16, 2), 256, 0, stream>>>(gbf, fc2T, pp, 2048, 1024, 4096);
  red_ln_pair<<<2048, 256, 0, stream>>>(pp, pp + 2097152, x1, (float*)d_out,
                                        pln_g, pln_b, w1, w2, xpi);

  pair_update<<<49152, 256, 0, stream>>>(x_pair, xpi, oc, (float*)d_out + 2097152);
}

// Round 11
// 293.277 us; speedup vs baseline: 1.0951x; 1.0547x over previous
//
#include <hip/hip_runtime.h>
#include <math.h>

// Shapes (fixed): L=512 B=4 D=1024 H=16 DH=64 FF=4096 HP=32 K=256, LK=768

typedef __bf16 bf16x8 __attribute__((ext_vector_type(8)));
typedef float f32x4 __attribute__((ext_vector_type(4)));

__device__ __forceinline__ unsigned short f2bf(float f) {
  unsigned u = __float_as_uint(f);
  u = (u + 0x7fffu + ((u >> 16) & 1u)) >> 16;
  return (unsigned short)u;
}
__device__ __forceinline__ float bf2f(unsigned short s) {
  return __uint_as_float(((unsigned)s) << 16);
}

__device__ __forceinline__ void gload_lds16(const void* g, void* l) {
  __builtin_amdgcn_global_load_lds(
      (__attribute__((address_space(1))) void*)g,
      (__attribute__((address_space(3))) void*)l, 16, 0, 0);
}

// ---- prep_all: weight transposes + top-LN + gathered-row LN + pos table -----
// blocks [0,6144): transposes; [6144,9216): LN rows; [9216,9228): posk
__global__ __launch_bounds__(256) void prep_all(
    const float* __restrict__ wq, const float* __restrict__ wk, const float* __restrict__ wv,
    const float* __restrict__ wo, const float* __restrict__ fc1, const float* __restrict__ fc2,
    const float* __restrict__ x, const int* __restrict__ oc, const int* __restrict__ pos_ids,
    const float* __restrict__ tln_g, const float* __restrict__ tln_b,
    unsigned short* __restrict__ qkvT, unsigned short* __restrict__ woT,
    unsigned short* __restrict__ fc1T, unsigned short* __restrict__ fc2T,
    unsigned short* __restrict__ kvb, int* __restrict__ posk) {
  __shared__ float smem[64 * 33];
  const int id = blockIdx.x, t = threadIdx.x;

  if (id < 6144) {  // ---- weight transpose branch (64k x 32n tiles) ----
    const float* W; unsigned short* WT; int Kd, Nd, n0, k0;
    if (id < 2048) {
      int which = id >> 9, lid = id & 511;
      W = which == 0 ? wq : (which == 1 ? wk : (which == 2 ? wv : wo));
      WT = which < 3 ? qkvT + (long)which * 1024 * 1024 : woT;
      Kd = 1024; Nd = 1024;
      k0 = (lid >> 5) * 64; n0 = (lid & 31) * 32;
    } else if (id < 4096) {
      int lid = id - 2048;
      W = fc1; WT = fc1T; Kd = 1024; Nd = 4096;
      k0 = (lid >> 7) * 64; n0 = (lid & 127) * 32;
    } else {
      int lid = id - 4096;
      W = fc2; WT = fc2T; Kd = 4096; Nd = 1024;
      k0 = (lid >> 5) * 64; n0 = (lid & 31) * 32;
    }
    const int tx = t & 31, ty = t >> 5;  // 32 x 8
#pragma unroll
    for (int j = 0; j < 64; j += 8)
      smem[(ty + j) * 33 + tx] = W[(long)(k0 + ty + j) * Nd + n0 + tx];
    __syncthreads();
#pragma unroll
    for (int i = 0; i < 32; i += 8) {
      ushort2 o;
      o.x = f2bf(smem[(2 * tx) * 33 + ty + i]);
      o.y = f2bf(smem[(2 * tx + 1) * 33 + ty + i]);
      *(ushort2*)&WT[(long)(n0 + ty + i) * Kd + k0 + 2 * tx] = o;
    }
  } else if (id < 9216) {  // ---- LN branch: kvb row = LN(x[src row]) ----
    const int rowIdx = id - 6144;  // 0..3071
    int srow;
    if (rowIdx < 2048) {
      srow = rowIdx;
    } else {
      int j = (rowIdx - 2048) >> 2, b = rowIdx & 3;
      srow = oc[b * 256 + j] * 4 + b;
    }
    const float4 vv = *(const float4*)(x + (long)srow * 1024 + t * 4);
    float s = vv.x + vv.y + vv.z + vv.w;
    float ss = vv.x * vv.x + vv.y * vv.y + vv.z * vv.z + vv.w * vv.w;
#pragma unroll
    for (int o = 32; o > 0; o >>= 1) { s += __shfl_down(s, o); ss += __shfl_down(ss, o); }
    const int wave = t >> 6, lane = t & 63;
    if (lane == 0) { smem[wave] = s; smem[4 + wave] = ss; }
    __syncthreads();
    s = smem[0] + smem[1] + smem[2] + smem[3];
    ss = smem[4] + smem[5] + smem[6] + smem[7];
    const float mean = s * (1.f / 1024.f);
    const float rstd = rsqrtf(ss * (1.f / 1024.f) - mean * mean + 1e-5f);
    const float4 gg = *(const float4*)(tln_g + t * 4);
    const float4 bbv = *(const float4*)(tln_b + t * 4);
    ushort4 o;
    o.x = f2bf((vv.x - mean) * rstd * gg.x + bbv.x);
    o.y = f2bf((vv.y - mean) * rstd * gg.y + bbv.y);
    o.z = f2bf((vv.z - mean) * rstd * gg.z + bbv.z);
    o.w = f2bf((vv.w - mean) * rstd * gg.w + bbv.w);
    *(ushort4*)&kvb[(long)rowIdx * 1024 + t * 4] = o;
  } else {  // ---- posk branch ----
    int i = (id - 9216) * 256 + t;
    if (i < 3072) {
      int s = i >> 2, b = i & 3;
      posk[i] = (s < 512) ? pos_ids[b * 512 + s]
                          : pos_ids[b * 512 + oc[b * 256 + s - 512]];
    }
  }
}

// ------- fused: v = sum of 4 splitk partials + R; Xout = v; Y = bf16(LN(v)) --
__global__ __launch_bounds__(256) void red_ln(
    const float* __restrict__ pp,
    const float* __restrict__ R, float* __restrict__ Xout,
    const float* __restrict__ g, const float* __restrict__ bb,
    unsigned short* __restrict__ Y) {
  const int row = blockIdx.x, t = threadIdx.x;
  const long base4 = (long)row * 256 + t;
  const float4 a0 = ((const float4*)pp)[base4];
  const float4 a1 = ((const float4*)pp)[base4 + 524288];
  const float4 a2 = ((const float4*)pp)[base4 + 2 * 524288];
  const float4 a3 = ((const float4*)pp)[base4 + 3 * 524288];
  const float4 r4 = ((const float4*)R)[base4];
  float4 v;
  v.x = a0.x + a1.x + a2.x + a3.x + r4.x;
  v.y = a0.y + a1.y + a2.y + a3.y + r4.y;
  v.z = a0.z + a1.z + a2.z + a3.z + r4.z;
  v.w = a0.w + a1.w + a2.w + a3.w + r4.w;
  ((float4*)Xout)[base4] = v;
  float s = v.x + v.y + v.z + v.w;
  float ss = v.x * v.x + v.y * v.y + v.z * v.z + v.w * v.w;
#pragma unroll
  for (int o = 32; o > 0; o >>= 1) { s += __shfl_down(s, o); ss += __shfl_down(ss, o); }
  __shared__ float red[8];
  const int wave = t >> 6, lane = t & 63;
  if (lane == 0) { red[wave] = s; red[4 + wave] = ss; }
  __syncthreads();
  s = red[0] + red[1] + red[2] + red[3];
  ss = red[4] + red[5] + red[6] + red[7];
  const float mean = s * (1.f / 1024.f);
  const float rstd = rsqrtf(ss * (1.f / 1024.f) - mean * mean + 1e-5f);
  const float4 gg = *(const float4*)(g + t * 4);
  const float4 bbv = *(const float4*)(bb + t * 4);
  ushort4 o;
  o.x = f2bf((v.x - mean) * rstd * gg.x + bbv.x);
  o.y = f2bf((v.y - mean) * rstd * gg.y + bbv.y);
  o.z = f2bf((v.z - mean) * rstd * gg.z + bbv.z);
  o.w = f2bf((v.w - mean) * rstd * gg.w + bbv.w);
  ((ushort4*)Y)[base4] = o;
}

// ---- fused: 4-partial reduce + residual + LN (f32) + pair head (silu@w2) ----
__global__ __launch_bounds__(256) void red_ln_pair(
    const float* __restrict__ pp,
    const float* __restrict__ R, float* __restrict__ Xout,
    const float* __restrict__ g, const float* __restrict__ bb,
    const float* __restrict__ w1, const float* __restrict__ w2,
    float* __restrict__ xpi) {
  const int row = blockIdx.x, t = threadIdx.x;
  const long base4 = (long)row * 256 + t;
  __shared__ float lnrow[1024];
  __shared__ float red[8];
  __shared__ float red2[64][4];
  __shared__ float s1[64];
  const float4 a0 = ((const float4*)pp)[base4];
  const float4 a1 = ((const float4*)pp)[base4 + 524288];
  const float4 a2 = ((const float4*)pp)[base4 + 2 * 524288];
  const float4 a3 = ((const float4*)pp)[base4 + 3 * 524288];
  const float4 r4 = ((const float4*)R)[base4];
  float4 v;
  v.x = a0.x + a1.x + a2.x + a3.x + r4.x;
  v.y = a0.y + a1.y + a2.y + a3.y + r4.y;
  v.z = a0.z + a1.z + a2.z + a3.z + r4.z;
  v.w = a0.w + a1.w + a2.w + a3.w + r4.w;
  ((float4*)Xout)[base4] = v;
  float s = v.x + v.y + v.z + v.w;
  float ss = v.x * v.x + v.y * v.y + v.z * v.z + v.w * v.w;
#pragma unroll
  for (int o = 32; o > 0; o >>= 1) { s += __shfl_down(s, o); ss += __shfl_down(ss, o); }
  const int wave = t >> 6, lane = t & 63;
  if (lane == 0) { red[wave] = s; red[4 + wave] = ss; }
  __syncthreads();
  s = red[0] + red[1] + red[2] + red[3];
  ss = red[4] + red[5] + red[6] + red[7];
  const float mean = s * (1.f / 1024.f);
  const float rstd = rsqrtf(ss * (1.f / 1024.f) - mean * mean + 1e-5f);
  const float4 gg = *(const float4*)(g + t * 4);
  const float4 bbv = *(const float4*)(bb + t * 4);
  float4 ln;
  ln.x = (v.x - mean) * rstd * gg.x + bbv.x;
  ln.y = (v.y - mean) * rstd * gg.y + bbv.y;
  ln.z = (v.z - mean) * rstd * gg.z + bbv.z;
  ln.w = (v.w - mean) * rstd * gg.w + bbv.w;
  *(float4*)&lnrow[t * 4] = ln;
  __syncthreads();
  const int c = t & 63, qt = t >> 6;
  float acc = 0.f;
  for (int k = qt * 256; k < qt * 256 + 256; k++)
    acc += lnrow[k] * w1[k * 64 + c];
  red2[c][qt] = acc;
  __syncthreads();
  if (t < 64) {
    float vv = red2[t][0] + red2[t][1] + red2[t][2] + red2[t][3];
    s1[t] = vv / (1.f + __expf(-vv));  // silu
  }
  __syncthreads();
  if (t < 32) {
    float o = 0.f;
    for (int k = 0; k < 64; k++) o += s1[k] * w2[k * 32 + t];
    xpi[(long)row * 32 + t] = o;
  }
}

// ---------------- MFMA bf16 NT GEMM, 128x128 tile, BK=32 ---------------------
// EPI: 0 = f32 out, 1 = f32 out + R, 2 = bf16 gelu(out), 3 = bf16 out
template <int EPI>
__global__ __launch_bounds__(256) void gemm_nt(
    const unsigned short* __restrict__ A, const unsigned short* __restrict__ BT,
    void* __restrict__ Cout, const float* __restrict__ R, int M, int N, int Kd) {
  __shared__ __align__(16) unsigned short As[128 * 32];
  __shared__ __align__(16) unsigned short Bs[128 * 32];
  const int t = threadIdx.x;
  const int wave = t >> 6, lane = t & 63;
  const int m0 = blockIdx.y * 128, n0 = blockIdx.x * 128;
  const int wr = wave >> 1, wc = wave & 1;
  const int lr = lane & 15, lg = lane >> 4;

  f32x4 acc[4][4] = {};

  const int srow = 32 * wave + (lane >> 2);
  const int schunk = (lane & 3) * 8;
  const unsigned short* Ag = A + (long)(m0 + srow) * Kd + schunk;
  const unsigned short* Bg = BT + (long)(n0 + srow) * Kd + schunk;
  unsigned short* AsW = &As[(32 * wave) * 32];
  unsigned short* BsW = &Bs[(32 * wave) * 32];

  for (int k0 = 0; k0 < Kd; k0 += 32) {
    __syncthreads();
    gload_lds16(Ag + k0, AsW);
    gload_lds16(Ag + k0 + 16 * (long)Kd, AsW + 16 * 32);
    gload_lds16(Bg + k0, BsW);
    gload_lds16(Bg + k0 + 16 * (long)Kd, BsW + 16 * 32);
    asm volatile("s_waitcnt vmcnt(0)" ::: "memory");
    __syncthreads();

    bf16x8 af[4], bfr[4];
#pragma unroll
    for (int mf = 0; mf < 4; mf++)
      af[mf] = *(const bf16x8*)&As[(64 * wr + 16 * mf + lr) * 32 + lg * 8];
#pragma unroll
    for (int nf = 0; nf < 4; nf++)
      bfr[nf] = *(const bf16x8*)&Bs[(64 * wc + 16 * nf + lr) * 32 + lg * 8];
#pragma unroll
    for (int mf = 0; mf < 4; mf++)
#pragma unroll
      for (int nf = 0; nf < 4; nf++)
        acc[mf][nf] = __builtin_amdgcn_mfma_f32_16x16x32_bf16(af[mf], bfr[nf], acc[mf][nf], 0, 0, 0);
  }

#pragma unroll
  for (int mf = 0; mf < 4; mf++)
#pragma unroll
    for (int nf = 0; nf < 4; nf++)
#pragma unroll
      for (int r = 0; r < 4; r++) {
        const int row = m0 + 64 * wr + 16 * mf + 4 * lg + r;
        const int col = n0 + 64 * wc + 16 * nf + lr;
        const long off = (long)row * N + col;
        float v = acc[mf][nf][r];
        if constexpr (EPI == 1) {
          ((float*)Cout)[off] = v + R[off];
        } else if constexpr (EPI == 2) {
          float gl = 0.5f * v * (1.0f + erff(v * 0.70710678118654752f));
          ((unsigned short*)Cout)[off] = f2bf(gl);
        } else if constexpr (EPI == 3) {
          ((unsigned short*)Cout)[off] = f2bf(v);
        } else {
          ((float*)Cout)[off] = v;
        }
      }
}

// -------- QKV GEMM: 1D grid, dead Q tiles (m>=16, n<8) skipped ---------------
__global__ __launch_bounds__(256) void gemm_qkv(
    const unsigned short* __restrict__ A, const unsigned short* __restrict__ BT,
    unsigned short* __restrict__ Cout) {
  constexpr int N = 3072, Kd = 1024;
  int bid = blockIdx.x;
  int mt, nt;
  if (bid < 384) { mt = bid / 24; nt = bid % 24; }
  else { int rem = bid - 384; mt = 16 + (rem >> 4); nt = 8 + (rem & 15); }
  const int m0 = mt * 128, n0 = nt * 128;

  __shared__ __align__(16) unsigned short As[128 * 32];
  __shared__ __align__(16) unsigned short Bs[128 * 32];
  const int t = threadIdx.x;
  const int wave = t >> 6, lane = t & 63;
  const int wr = wave >> 1, wc = wave & 1;
  const int lr = lane & 15, lg = lane >> 4;

  f32x4 acc[4][4] = {};

  const int srow = 32 * wave + (lane >> 2);
  const int schunk = (lane & 3) * 8;
  const unsigned short* Ag = A + (long)(m0 + srow) * Kd + schunk;
  const unsigned short* Bg = BT + (long)(n0 + srow) * Kd + schunk;
  unsigned short* AsW = &As[(32 * wave) * 32];
  unsigned short* BsW = &Bs[(32 * wave) * 32];

  for (int k0 = 0; k0 < Kd; k0 += 32) {
    __syncthreads();
    gload_lds16(Ag + k0, AsW);
    gload_lds16(Ag + k0 + 16 * (long)Kd, AsW + 16 * 32);
    gload_lds16(Bg + k0, BsW);
    gload_lds16(Bg + k0 + 16 * (long)Kd, BsW + 16 * 32);
    asm volatile("s_waitcnt vmcnt(0)" ::: "memory");
    __syncthreads();

    bf16x8 af[4], bfr[4];
#pragma unroll
    for (int mf = 0; mf < 4; mf++)
      af[mf] = *(const bf16x8*)&As[(64 * wr + 16 * mf + lr) * 32 + lg * 8];
#pragma unroll
    for (int nf = 0; nf < 4; nf++)
      bfr[nf] = *(const bf16x8*)&Bs[(64 * wc + 16 * nf + lr) * 32 + lg * 8];
#pragma unroll
    for (int mf = 0; mf < 4; mf++)
#pragma unroll
      for (int nf = 0; nf < 4; nf++)
        acc[mf][nf] = __builtin_amdgcn_mfma_f32_16x16x32_bf16(af[mf], bfr[nf], acc[mf][nf], 0, 0, 0);
  }

#pragma unroll
  for (int mf = 0; mf < 4; mf++)
#pragma unroll
    for (int nf = 0; nf < 4; nf++)
#pragma unroll
      for (int r = 0; r < 4; r++) {
        const int row = m0 + 64 * wr + 16 * mf + 4 * lg + r;
        const int col = n0 + 64 * wc + 16 * nf + lr;
        Cout[(long)row * N + col] = f2bf(acc[mf][nf][r]);
      }
}

// ----- split-K variant: partial f32 C per blockIdx.z (split = gridDim.z) -----
__global__ __launch_bounds__(256) void gemm_nt_splitk(
    const unsigned short* __restrict__ A, const unsigned short* __restrict__ BT,
    float* __restrict__ Cp, int M, int N, int Kd) {
  const int kh = Kd / gridDim.z;
  const long kbase = (long)blockIdx.z * kh;
  const unsigned short* A2 = A + kbase;
  const unsigned short* B2 = BT + kbase;
  float* Cz = Cp + (long)blockIdx.z * M * N;

  __shared__ __align__(16) unsigned short As[128 * 32];
  __shared__ __align__(16) unsigned short Bs[128 * 32];
  const int t = threadIdx.x;
  const int wave = t >> 6, lane = t & 63;
  const int m0 = blockIdx.y * 128, n0 = blockIdx.x * 128;
  const int wr = wave >> 1, wc = wave & 1;
  const int lr = lane & 15, lg = lane >> 4;

  f32x4 acc[4][4] = {};

  const int srow = 32 * wave + (lane >> 2);
  const int schunk = (lane & 3) * 8;
  const unsigned short* Ag = A2 + (long)(m0 + srow) * Kd + schunk;
  const unsigned short* Bg = B2 + (long)(n0 + srow) * Kd + schunk;
  unsigned short* AsW = &As[(32 * wave) * 32];
  unsigned short* BsW = &Bs[(32 * wave) * 32];

  for (int k0 = 0; k0 < kh; k0 += 32) {
    __syncthreads();
    gload_lds16(Ag + k0, AsW);
    gload_lds16(Ag + k0 + 16 * (long)Kd, AsW + 16 * 32);
    gload_lds16(Bg + k0, BsW);
    gload_lds16(Bg + k0 + 16 * (long)Kd, BsW + 16 * 32);
    asm volatile("s_waitcnt vmcnt(0)" ::: "memory");
    __syncthreads();

    bf16x8 af[4], bfr[4];
#pragma unroll
    for (int mf = 0; mf < 4; mf++)
      af[mf] = *(const bf16x8*)&As[(64 * wr + 16 * mf + lr) * 32 + lg * 8];
#pragma unroll
    for (int nf = 0; nf < 4; nf++)
      bfr[nf] = *(const bf16x8*)&Bs[(64 * wc + 16 * nf + lr) * 32 + lg * 8];
#pragma unroll
    for (int mf = 0; mf < 4; mf++)
#pragma unroll
      for (int nf = 0; nf < 4; nf++)
        acc[mf][nf] = __builtin_amdgcn_mfma_f32_16x16x32_bf16(af[mf], bfr[nf], acc[mf][nf], 0, 0, 0);
  }

#pragma unroll
  for (int mf = 0; mf < 4; mf++)
#pragma unroll
    for (int nf = 0; nf < 4; nf++)
#pragma unroll
      for (int r = 0; r < 4; r++) {
        const int row = m0 + 64 * wr + 16 * mf + 4 * lg + r;
        const int col = n0 + 64 * wc + 16 * nf + lr;
        Cz[(long)row * N + col] = acc[mf][nf][r];
      }
}

// ---- rope_vt: RoPE split (blocks < 5120, ushort2) + V transpose (>= 5120) ---
// qb: [bh][512][64] bf16 scaled 1/8;  kbh: [bh][768][64];  vth: [bh][64][768]
__global__ __launch_bounds__(256) void rope_vt(
    const unsigned short* __restrict__ QKV, const int* __restrict__ posk,
    unsigned short* __restrict__ qb, unsigned short* __restrict__ kbh,
    unsigned short* __restrict__ vth) {
  const int bid = blockIdx.x, t = threadIdx.x;
  if (bid < 5120) {  // ---- RoPE branch: 2 dp per thread ----
    int idx = bid * 256 + t;  // 524288 q-pairs + 786432 k-pairs
    bool isq = idx < 524288;
    int rp = isq ? idx : idx - 524288;
    int p = rp & 255;          // 256 threads per row
    int row = rp >> 8;         // row = s*4+b
    int hh = p >> 4, dpp = (p & 15) * 2;
    int s = row >> 2, b = row & 3;
    int pos = posk[s * 4 + b];
    const unsigned short* src = QKV + (long)row * 3072 + (isq ? 0 : 1024) + hh * 64 + dpp;
    ushort2 xa = *(const ushort2*)src;         // dp, dp+1 (first half)
    ushort2 xb = *(const ushort2*)(src + 32);  // dp+32, dp+33 (second half)
    const float cfr = 0.41524101186091903f;    // log2(10000)/32
    float i0 = exp2f(-(float)dpp * cfr);
    float i1 = exp2f(-(float)(dpp + 1) * cfr);
    float s0, c0, s1, c1;
    __sincosf((float)pos * i0, &s0, &c0);
    __sincosf((float)pos * i1, &s1, &c1);
    float x1a = bf2f(xa.x), x1b = bf2f(xa.y);
    float x2a = bf2f(xb.x), x2b = bf2f(xb.y);
    float qs = isq ? 0.125f : 1.0f;
    ushort2 o1, o2;
    o1.x = f2bf((x1a * c0 - x2a * s0) * qs);
    o1.y = f2bf((x1b * c1 - x2b * s1) * qs);
    o2.x = f2bf((x1a * s0 + x2a * c0) * qs);
    o2.y = f2bf((x1b * s1 + x2b * c1) * qs);
    unsigned short* dst = (isq ? qb + ((long)(b * 16 + hh) * 512 + s) * 64
                               : kbh + ((long)(b * 16 + hh) * 768 + s) * 64) + dpp;
    *(ushort2*)dst = o1;
    *(ushort2*)(dst + 32) = o2;
  } else {  // ---- V transpose branch ----
    __shared__ unsigned short tile[64][72];
    const int vb = bid - 5120;           // 0..767
    const int kt = vb % 12, bh = vb / 12;
    const int b = bh >> 4, h = bh & 15;
    const int key = t >> 2, c = t & 3;
    const unsigned short* src =
        QKV + ((long)(kt * 64 + key) * 4 + b) * 3072 + 2048 + h * 64 + c * 16;
#pragma unroll
    for (int j = 0; j < 16; j++) tile[c * 16 + j][key] = src[j];
    __syncthreads();
    const int d = t >> 2;
    unsigned short* dst = vth + ((long)bh * 64 + d) * 768 + kt * 64 + c * 16;
    *(uint4*)dst = *(const uint4*)&tile[d][c * 16];
    *(uint4*)(dst + 8) = *(const uint4*)&tile[d][c * 16 + 8];
  }
}

// -- MFMA flash attention, barrier-free: fragments direct from global (L1/L2) -
__global__ __launch_bounds__(512) void att_mfma(
    const unsigned short* __restrict__ qb, const unsigned short* __restrict__ kbh,
    const unsigned short* __restrict__ vth,
    const unsigned char* __restrict__ pad_mask, const unsigned char* __restrict__ exp_mask,
    unsigned short* __restrict__ o_bf) {
  const int bh = blockIdx.y, b = bh >> 4, h = bh & 15;
  const int q0 = blockIdx.x * 128;
  const int t = threadIdx.x, wave = t >> 6, lane = t & 63;
  const int lr = lane & 15, lg = lane >> 4;

  __shared__ __align__(16) unsigned short Ps[8][16][72];
  __shared__ float maskAdd[768];

  for (int i = t; i < 768; i += 512)
    maskAdd[i] = ((i < 512) ? pad_mask[b * 512 + i] : exp_mask[b * 256 + i - 512]) ? -1e9f : 0.f;

  const unsigned short* qrow = qb + ((long)bh * 512 + q0 + wave * 16 + lr) * 64;
  const bf16x8 aq0 = *(const bf16x8*)(qrow + lg * 8);
  const bf16x8 aq1 = *(const bf16x8*)(qrow + 32 + lg * 8);
  __syncthreads();  // maskAdd ready; no further barriers in the K-loop

  float m_run[4] = {-1e30f, -1e30f, -1e30f, -1e30f};
  float l_run[4] = {0.f, 0.f, 0.f, 0.f};
  f32x4 Oacc[4] = {};

  const unsigned short* kb0 = kbh + (long)bh * 768 * 64;
  const unsigned short* vb0 = vth + (long)bh * 64 * 768;

  for (int kt = 0; kt < 12; ++kt) {
    float sv[4][4];
#pragma unroll
    for (int nf = 0; nf < 4; nf++) {
      const unsigned short* kr = kb0 + (long)(kt * 64 + nf * 16 + lr) * 64;
      f32x4 z = {};
      bf16x8 b0 = *(const bf16x8*)(kr + lg * 8);
      bf16x8 b1 = *(const bf16x8*)(kr + 32 + lg * 8);
      z = __builtin_amdgcn_mfma_f32_16x16x32_bf16(aq0, b0, z, 0, 0, 0);
      z = __builtin_amdgcn_mfma_f32_16x16x32_bf16(aq1, b1, z, 0, 0, 0);
      float ma = maskAdd[kt * 64 + nf * 16 + lr];
#pragma unroll
      for (int r = 0; r < 4; r++) sv[nf][r] = z[r] + ma;
    }
    float mnew[4], scale[4], rs[4];
#pragma unroll
    for (int r = 0; r < 4; r++) {
      float tm = fmaxf(fmaxf(sv[0][r], sv[1][r]), fmaxf(sv[2][r], sv[3][r]));
      tm = fmaxf(tm, __shfl_xor(tm, 1));
      tm = fmaxf(tm, __shfl_xor(tm, 2));
      tm = fmaxf(tm, __shfl_xor(tm, 4));
      tm = fmaxf(tm, __shfl_xor(tm, 8));
      mnew[r] = fmaxf(m_run[r], tm);
      scale[r] = __expf(m_run[r] - mnew[r]);
      m_run[r] = mnew[r];
      rs[r] = 0.f;
    }
#pragma unroll
    for (int nf = 0; nf < 4; nf++)
#pragma unroll
      for (int r = 0; r < 4; r++) {
        float p = __expf(sv[nf][r] - mnew[r]);
        rs[r] += p;
        Ps[wave][lg * 4 + r][nf * 16 + lr] = f2bf(p);
      }
#pragma unroll
    for (int r = 0; r < 4; r++) {
      float x = rs[r];
      x += __shfl_xor(x, 1); x += __shfl_xor(x, 2);
      x += __shfl_xor(x, 4); x += __shfl_xor(x, 8);
      l_run[r] = l_run[r] * scale[r] + x;
#pragma unroll
      for (int nf = 0; nf < 4; nf++) Oacc[nf][r] *= scale[r];
    }
    bf16x8 ap0 = *(const bf16x8*)&Ps[wave][lr][lg * 8];
    bf16x8 ap1 = *(const bf16x8*)&Ps[wave][lr][32 + lg * 8];
#pragma unroll
    for (int nf = 0; nf < 4; nf++) {
      const unsigned short* vr = vb0 + (long)(nf * 16 + lr) * 768 + kt * 64;
      bf16x8 b0 = *(const bf16x8*)(vr + lg * 8);
      bf16x8 b1 = *(const bf16x8*)(vr + 32 + lg * 8);
      Oacc[nf] = __builtin_amdgcn_mfma_f32_16x16x32_bf16(ap0, b0, Oacc[nf], 0, 0, 0);
      Oacc[nf] = __builtin_amdgcn_mfma_f32_16x16x32_bf16(ap1, b1, Oacc[nf], 0, 0, 0);
    }
  }

#pragma unroll
  for (int r = 0; r < 4; r++) {
    float inv = 1.0f / l_run[r];
    int l = q0 + wave * 16 + lg * 4 + r;
#pragma unroll
    for (int nf = 0; nf < 4; nf++)
      o_bf[(((long)l * 4 + b) * 16 + h) * 64 + nf * 16 + lr] = f2bf(Oacc[nf][r] * inv);
  }
}

// ------------ x_pair += outer(x_p_i, x_p_j) with inline oc gather ------------
// Flat grid (49152 blocks): one float4 per thread, max memory-level parallelism.
__global__ __launch_bounds__(256) void pair_update(
    const float* __restrict__ x_pair, const float* __restrict__ xpi,
    const int* __restrict__ oc, float* __restrict__ out) {
  int idx4 = blockIdx.x * 256 + threadIdx.x;  // 12582912 float4s
  int h4 = idx4 & 7;
  int lkb = idx4 >> 3;
  int b = lkb & 3;
  int lk = lkb >> 2;
  int kk = lk % 768;
  int l = lk / 768;
  int src = (kk < 512) ? kk : oc[b * 256 + kk - 512];
  float4 pv = ((const float4*)x_pair)[idx4];
  float4 a = ((const float4*)xpi)[(l * 4 + b) * 8 + h4];
  float4 bb = ((const float4*)xpi)[(src * 4 + b) * 8 + h4];
  float4 o;
  o.x = pv.x + a.x * bb.x; o.y = pv.y + a.y * bb.y;
  o.z = pv.z + a.z * bb.z; o.w = pv.w + a.w * bb.w;
  ((float4*)out)[idx4] = o;
}

// =============================== launcher ====================================
extern "C" void kernel_launch(void* const* d_in, const int* in_sizes, int n_in,
                              void* d_out, int out_size, void* d_ws, size_t ws_size,
                              hipStream_t stream) {
  const float* x        = (const float*)d_in[0];
  const float* x_pair   = (const float*)d_in[1];
  const unsigned char* pad_mask = (const unsigned char*)d_in[2];
  const unsigned char* exp_mask = (const unsigned char*)d_in[3];
  const int* pos_ids    = (const int*)d_in[4];
  const int* oc         = (const int*)d_in[5];
  const float* wq  = (const float*)d_in[6];
  const float* wk  = (const float*)d_in[7];
  const float* wv  = (const float*)d_in[8];
  const float* wo  = (const float*)d_in[9];
  const float* fc1 = (const float*)d_in[10];
  const float* fc2 = (const float*)d_in[11];
  const float* tln_g = (const float*)d_in[12];
  const float* tln_b = (const float*)d_in[13];
  const float* mln_g = (const float*)d_in[14];
  const float* mln_b = (const float*)d_in[15];
  const float* pln_g = (const float*)d_in[16];
  const float* pln_b = (const float*)d_in[17];
  const float* w1 = (const float*)d_in[18];
  const float* w2 = (const float*)d_in[19];

  char* wsp = (char*)d_ws;
  size_t off = 0;
  auto alloc = [&](size_t bytes) -> void* {
    void* p = wsp + off;
    off = (off + bytes + 255) & ~(size_t)255;
    return p;
  };
  unsigned short* qkvT = (unsigned short*)alloc(3072LL * 1024 * 2);
  unsigned short* woT  = (unsigned short*)alloc(1024LL * 1024 * 2);
  unsigned short* fc1T = (unsigned short*)alloc(4096LL * 1024 * 2);
  unsigned short* fc2T = (unsigned short*)alloc(1024LL * 4096 * 2);
  unsigned short* kvb  = (unsigned short*)alloc(3072LL * 1024 * 2);
  int* posk            = (int*)alloc(3072LL * 4);
  unsigned short* QKVb = (unsigned short*)alloc(3072LL * 3072 * 2);
  unsigned short* qb   = (unsigned short*)alloc(64LL * 512 * 64 * 2);
  unsigned short* kbh  = (unsigned short*)alloc(64LL * 768 * 64 * 2);
  unsigned short* vth  = (unsigned short*)alloc(64LL * 64 * 768 * 2);
  unsigned short* obf  = (unsigned short*)alloc(2048LL * 1024 * 2);
  float* x1            = (float*)alloc(2048LL * 1024 * 4);
  unsigned short* h2   = (unsigned short*)alloc(2048LL * 1024 * 2);
  unsigned short* gbf  = (unsigned short*)alloc(2048LL * 4096 * 2);
  float* xpi           = (float*)alloc(2048LL * 32 * 4);
  float* pp            = (float*)alloc(4LL * 2048 * 1024 * 4);  // split-K=4 partials
  (void)ws_size; (void)in_sizes; (void)n_in; (void)out_size;

  // prep: weight transposes + top-LN (incl. gathered rows) + pos table
  prep_all<<<9228, 256, 0, stream>>>(wq, wk, wv, wo, fc1, fc2, x, oc, pos_ids,
                                     tln_g, tln_b, qkvT, woT, fc1T, fc2T, kvb, posk);

  // QKV GEMM (dead Q tiles skipped), bf16 out
  gemm_qkv<<<512, 256, 0, stream>>>(kvb, qkvT, QKVb);

  // RoPE split + V transpose in one launch
  rope_vt<<<5888, 256, 0, stream>>>(QKVb, posk, qb, kbh, vth);

  att_mfma<<<dim3(4, 64), 512, 0, stream>>>(qb, kbh, vth, pad_mask, exp_mask, obf);

  // x1 = x + attn_out @ wo  (split-K=4 + fused reduce+residual+LN -> h2)
  gemm_nt_splitk<<<dim3(8, 16, 4), 256, 0, stream>>>(obf, woT, pp, 2048, 1024, 1024);
  red_ln<<<2048, 256, 0, stream>>>(pp, x, x1, mln_g, mln_b, h2);

  gemm_nt<2><<<dim3(32, 16), 256, 0, stream>>>(h2, fc1T, gbf, nullptr, 2048, 4096, 1024);

  // x = x1 + gelu @ fc2  (split-K=4 + fused reduce+residual+LN+pairhead)
  gemm_nt_splitk<<<dim3(8, 16, 4), 256, 0, stream>>>(gbf, fc2T, pp, 2048, 1024, 4096);
  red_ln_pair<<<2048, 256, 0, stream>>>(pp, x1, (float*)d_out,
                                        pln_g, pln_b, w1, w2, xpi);

  pair_update<<<49152, 256, 0, stream>>>(x_pair, xpi, oc, (float*)d_out + 2097152);
}